// Round 5
// baseline (2746.859 us; speedup 1.0000x reference)
//
#include <hip/hip_runtime.h>

#define N_NODES 100000
#define E_EDGES 1600000
#define IN_F 128
#define H_F 256
#define K_HOPS 7
#define R_REL 5
#define OUT_W (R_REL * H_F)  // 1280

typedef __attribute__((ext_vector_type(8))) short short8;
typedef __attribute__((ext_vector_type(4))) float f32x4;

// ---------------- small utility kernels ----------------

__global__ void zero_int(int* __restrict__ p, int n) {
    int t = blockIdx.x * blockDim.x + threadIdx.x;
    if (t < n) p[t] = 0;
}

__global__ void deg_count(const int* __restrict__ row, int* __restrict__ deg) {
    int e = blockIdx.x * blockDim.x + threadIdx.x;
    if (e < E_EDGES) atomicAdd(&deg[row[e]], 1);
}

__global__ void dinv_compute(const int* __restrict__ deg, float* __restrict__ dinv) {
    int i = blockIdx.x * blockDim.x + threadIdx.x;
    if (i < N_NODES) dinv[i] = rsqrtf((float)(deg[i] + 1));
}

// exclusive scan of deg[N] -> rowptr[N+1], single 1024-thread block
__global__ __launch_bounds__(1024) void exscan_rowptr(const int* __restrict__ deg,
                                                      int* __restrict__ rowptr) {
    __shared__ int wsum[16];
    __shared__ int carry_s;
    const int t = threadIdx.x, lane = t & 63, wv = t >> 6;
    if (t == 0) carry_s = 0;
    __syncthreads();
    for (int base = 0; base < N_NODES; base += 1024) {
        int i = base + t;
        int v = (i < N_NODES) ? deg[i] : 0;
        int x = v;
#pragma unroll
        for (int off = 1; off < 64; off <<= 1) {
            int n = __shfl_up(x, off, 64);
            if (lane >= off) x += n;
        }
        if (lane == 63) wsum[wv] = x;
        __syncthreads();
        if (wv == 0 && lane < 16) {
            int s = wsum[lane];
#pragma unroll
            for (int off = 1; off < 16; off <<= 1) {
                int n = __shfl_up(s, off, 64);
                if (lane >= off) s += n;
            }
            wsum[lane] = s;
        }
        __syncthreads();
        int wbase = (wv == 0) ? 0 : wsum[wv - 1];
        if (i < N_NODES) rowptr[i] = carry_s + wbase + x - v;
        __syncthreads();
        if (t == 1023) carry_s += wsum[15];
        __syncthreads();
    }
    if (threadIdx.x == 0) rowptr[N_NODES] = carry_s;
}

__global__ void csr_scatter(const int* __restrict__ row, const int* __restrict__ col,
                            const float* __restrict__ dinv, const int* __restrict__ rowptr,
                            int* __restrict__ cursor, int* __restrict__ cols2,
                            float* __restrict__ ew) {
    int e = blockIdx.x * blockDim.x + threadIdx.x;
    if (e >= E_EDGES) return;
    int r = row[e], c = col[e];
    int pos = rowptr[r] + atomicAdd(&cursor[r], 1);
    cols2[pos] = c;
    ew[pos] = dinv[r] * dinv[c];
}

// ---------------- bf16 split helpers ----------------

__device__ __forceinline__ void f2bf_split(float v, short& h, short& l) {
    unsigned u = __float_as_uint(v);
    unsigned hb = (u + 0x7FFFu + ((u >> 16) & 1u)) >> 16;  // RN-to-even bf16
    float fh = __uint_as_float(hb << 16);
    float r = v - fh;
    unsigned u2 = __float_as_uint(r);
    unsigned lb = (u2 + 0x7FFFu + ((u2 >> 16) & 1u)) >> 16;
    h = (short)(unsigned short)hb;
    l = (short)(unsigned short)lb;
}

__device__ __forceinline__ int pack2(short a, short b) {
    return (int)(unsigned short)a | ((int)(unsigned short)b << 16);
}

// elementwise split: in fp32[4t..4t+3] -> oh/ol bf16
__global__ void split_pack(const float4* __restrict__ in, int2* __restrict__ oh,
                           int2* __restrict__ ol, int n4) {
    int t = blockIdx.x * blockDim.x + threadIdx.x;
    if (t >= n4) return;
    float4 v = in[t];
    short h0, l0, h1, l1, h2, l2, h3, l3;
    f2bf_split(v.x, h0, l0);
    f2bf_split(v.y, h1, l1);
    f2bf_split(v.z, h2, l2);
    f2bf_split(v.w, h3, l3);
    oh[t] = make_int2(pack2(h0, h1), pack2(h2, h3));
    ol[t] = make_int2(pack2(l0, l1), pack2(l2, l3));
}

// y[i] = dinv[i]^2 * x[i] + sum_j w[j] * x[cols[j]]   (one wave per row, float2/lane)
// also emits split-bf16 copy of y (packed 2 shorts per int)
__global__ __launch_bounds__(256) void spmm_csr(
    const float2* __restrict__ x, const int* __restrict__ rowptr,
    const int* __restrict__ cols, const float* __restrict__ w,
    const float* __restrict__ dinv, float2* __restrict__ y,
    int* __restrict__ yh, int* __restrict__ yl) {
    const int wave = threadIdx.x >> 6, lane = threadIdx.x & 63;
    const int i = blockIdx.x * 4 + wave;
    if (i >= N_NODES) return;
    const float d = dinv[i];
    float2 xv = x[(size_t)i * 64 + lane];
    float2 acc;
    acc.x = d * d * xv.x;
    acc.y = d * d * xv.y;
    int j = rowptr[i];
    const int e = rowptr[i + 1];
    for (; j + 3 < e; j += 4) {
        int c0 = cols[j], c1 = cols[j + 1], c2 = cols[j + 2], c3 = cols[j + 3];
        float w0 = w[j], w1 = w[j + 1], w2 = w[j + 2], w3 = w[j + 3];
        float2 v0 = x[(size_t)c0 * 64 + lane];
        float2 v1 = x[(size_t)c1 * 64 + lane];
        float2 v2 = x[(size_t)c2 * 64 + lane];
        float2 v3 = x[(size_t)c3 * 64 + lane];
        acc.x += w0 * v0.x + w1 * v1.x + w2 * v2.x + w3 * v3.x;
        acc.y += w0 * v0.y + w1 * v1.y + w2 * v2.y + w3 * v3.y;
    }
    for (; j < e; ++j) {
        int c0 = cols[j];
        float w0 = w[j];
        float2 v0 = x[(size_t)c0 * 64 + lane];
        acc.x += w0 * v0.x;
        acc.y += w0 * v0.y;
    }
    y[(size_t)i * 64 + lane] = acc;
    short hx, lx, hy, ly;
    f2bf_split(acc.x, hx, lx);
    f2bf_split(acc.y, hy, ly);
    yh[(size_t)i * 64 + lane] = pack2(hx, hy);
    yl[(size_t)i * 64 + lane] = pack2(lx, ly);
}

// ---------------- weight-fusion precompute ----------------
// Wc[z=r*3+d] = W2[r+d] @ WrS[r,d]
__global__ __launch_bounds__(256) void wc_compute(const float* __restrict__ W2,
                                                  const float* __restrict__ Wr,
                                                  float* __restrict__ Wc) {
    const int z = blockIdx.x, j = blockIdx.y, g = threadIdx.x;
    const int r = z / 3, d = z % 3, hop = r + d;
    const float* a = W2 + (size_t)hop * H_F * H_F + (size_t)j * H_F;
    const float* b = Wr + ((size_t)r * 768 + (size_t)d * H_F) * H_F + g;
    float acc = 0.f;
#pragma unroll 4
    for (int h = 0; h < H_F; ++h) acc += a[h] * b[(size_t)h * H_F];
    Wc[(size_t)z * H_F * H_F + (size_t)j * H_F + g] = acc;
}

// bc[r] = br[r] + sum_{d,h} b2[r+d][h] * WrS[r,d][h][:]
__global__ __launch_bounds__(256) void bc_compute(const float* __restrict__ b2,
                                                  const float* __restrict__ Wr,
                                                  const float* __restrict__ br,
                                                  float* __restrict__ bc) {
    const int r = blockIdx.x, g = threadIdx.x;
    float acc = br[(size_t)r * H_F + g];
    for (int t = 0; t < 3 * H_F; ++t) {
        float bv = b2[(size_t)(r + t / H_F) * H_F + (t % H_F)];
        acc += bv * Wr[((size_t)r * 768 + t) * H_F + g];
    }
    bc[(size_t)r * H_F + g] = acc;
}

// weight transpose+split: in [z][Kd][256] fp32 -> BT groups: out group (z/grp) is
// [256][grp*Kd] bf16, z%grp selects the Kd-column slab.  grid (Kd/32, 8, nz), block (32,8)
__global__ void transpose_convert(const float* __restrict__ in, short* __restrict__ oh,
                                  short* __restrict__ ol, int Kd, int grp) {
    __shared__ float t[32][33];
    const int i0 = blockIdx.x * 32, n0 = blockIdx.y * 32, z = blockIdx.z;
    const int tx = threadIdx.x, ty = threadIdx.y;
    const int outLd = grp * Kd;
    const float* ip = in + (size_t)z * Kd * 256;
#pragma unroll
    for (int j = 0; j < 4; ++j)
        t[ty + 8 * j][tx] = ip[(size_t)(i0 + ty + 8 * j) * 256 + n0 + tx];
    __syncthreads();
    size_t base = (size_t)(z / grp) * 256 * outLd + (size_t)(z % grp) * Kd;
#pragma unroll
    for (int j = 0; j < 4; ++j) {
        float v = t[tx][ty + 8 * j];
        short hb, lb;
        f2bf_split(v, hb, lb);
        size_t o = base + (size_t)(n0 + ty + 8 * j) * outLd + i0 + tx;
        oh[o] = hb;
        ol[o] = lb;
    }
}

// ---------------- split-bf16 MFMA GEMM (pre-split A and B) ----------------
// C[M,256-slice] = A[M,K] @ B[K,256] (+bias) (+relu) (+accum)
// block tile 128x128, 4 waves (2M x 2N), wave tile 64x64, BK=32
// A spans hops: element (m, k) at Ag* + (k>>8)*hopStride + (k&255) + m*lda
// MODE: 0 = bias, 1 = bias+relu, 2 = accum, 3 = accum+relu
// OUTSPLIT: write C as split bf16 into Ch/Cl instead of fp32 C.

#define LROW 40

template <int MODE, bool OUTSPLIT>
__global__ __launch_bounds__(256, 2) void gemm_split(
    const short* __restrict__ Agh, const short* __restrict__ Agl, int lda, long hopStride,
    const short* __restrict__ BTh, const short* __restrict__ BTl, int ldb, int Kd,
    float* __restrict__ C, short* __restrict__ Ch, short* __restrict__ Cl, int ldc,
    const float* __restrict__ bias, int M)
{
    __shared__ short lds_buf[4 * 128 * LROW];
    short* Ah = lds_buf;
    short* Al = lds_buf + 128 * LROW;
    short* Bh = lds_buf + 2 * 128 * LROW;
    short* Bl = lds_buf + 3 * 128 * LROW;

    const int tid = threadIdx.x;
    const int lane = tid & 63, wave = tid >> 6;
    const int wm = wave & 1, wn = wave >> 1;
    const int fr = lane & 15, fg = lane >> 4;
    const int m0 = blockIdx.y * 128;
    const int n0 = blockIdx.x * 128;

    const int sr = tid >> 1;
    const int sc = (tid & 1) * 16;
    const bool avalid = (m0 + sr) < M;
    const int arow = avalid ? (m0 + sr) : (M - 1);

    short8 gah[2], gal[2], gbh[2], gbl[2];

    {
        const short* aph = Agh + (size_t)arow * lda + sc;
        const short* apl = Agl + (size_t)arow * lda + sc;
        const short* bph = BTh + (size_t)(n0 + sr) * ldb + sc;
        const short* bpl = BTl + (size_t)(n0 + sr) * ldb + sc;
        gah[0] = *(const short8*)aph;  gah[1] = *(const short8*)(aph + 8);
        gal[0] = *(const short8*)apl;  gal[1] = *(const short8*)(apl + 8);
        gbh[0] = *(const short8*)bph;  gbh[1] = *(const short8*)(bph + 8);
        gbl[0] = *(const short8*)bpl;  gbl[1] = *(const short8*)(bpl + 8);
    }

    f32x4 acc[4][4];
#pragma unroll
    for (int i = 0; i < 4; ++i)
#pragma unroll
        for (int j = 0; j < 4; ++j) acc[i][j] = (f32x4)0.f;

    const int nk = Kd / 32;
    for (int kk = 0; kk < nk; ++kk) {
        __syncthreads();
        *(short8*)(Ah + sr * LROW + sc)     = gah[0];
        *(short8*)(Ah + sr * LROW + sc + 8) = gah[1];
        *(short8*)(Al + sr * LROW + sc)     = gal[0];
        *(short8*)(Al + sr * LROW + sc + 8) = gal[1];
        *(short8*)(Bh + sr * LROW + sc)     = gbh[0];
        *(short8*)(Bh + sr * LROW + sc + 8) = gbh[1];
        *(short8*)(Bl + sr * LROW + sc)     = gbl[0];
        *(short8*)(Bl + sr * LROW + sc + 8) = gbl[1];
        __syncthreads();

        if (kk + 1 < nk) {
            int k0 = (kk + 1) * 32;
            const short* aph = Agh + (size_t)(k0 >> 8) * hopStride + (k0 & 255)
                               + (size_t)arow * lda + sc;
            const short* apl = Agl + (size_t)(k0 >> 8) * hopStride + (k0 & 255)
                               + (size_t)arow * lda + sc;
            const short* bph = BTh + (size_t)(n0 + sr) * ldb + k0 + sc;
            const short* bpl = BTl + (size_t)(n0 + sr) * ldb + k0 + sc;
            gah[0] = *(const short8*)aph;  gah[1] = *(const short8*)(aph + 8);
            gal[0] = *(const short8*)apl;  gal[1] = *(const short8*)(apl + 8);
            gbh[0] = *(const short8*)bph;  gbh[1] = *(const short8*)(bph + 8);
            gbl[0] = *(const short8*)bpl;  gbl[1] = *(const short8*)(bpl + 8);
        }

        short8 afh[4], afl[4], bfh[4], bfl[4];
#pragma unroll
        for (int mf = 0; mf < 4; ++mf) {
            int r = wm * 64 + mf * 16 + fr;
            afh[mf] = *(const short8*)(Ah + r * LROW + fg * 8);
            afl[mf] = *(const short8*)(Al + r * LROW + fg * 8);
        }
#pragma unroll
        for (int nf = 0; nf < 4; ++nf) {
            int r = wn * 64 + nf * 16 + fr;
            bfh[nf] = *(const short8*)(Bh + r * LROW + fg * 8);
            bfl[nf] = *(const short8*)(Bl + r * LROW + fg * 8);
        }
#pragma unroll
        for (int mf = 0; mf < 4; ++mf)
#pragma unroll
            for (int nf = 0; nf < 4; ++nf) {
                acc[mf][nf] = __builtin_amdgcn_mfma_f32_16x16x32_bf16(
                    afh[mf], bfh[nf], acc[mf][nf], 0, 0, 0);
                acc[mf][nf] = __builtin_amdgcn_mfma_f32_16x16x32_bf16(
                    afh[mf], bfl[nf], acc[mf][nf], 0, 0, 0);
                acc[mf][nf] = __builtin_amdgcn_mfma_f32_16x16x32_bf16(
                    afl[mf], bfh[nf], acc[mf][nf], 0, 0, 0);
            }
    }

    // epilogue: C/D layout col=lane&15, row=(lane>>4)*4+reg
#pragma unroll
    for (int nf = 0; nf < 4; ++nf) {
        int colg = n0 + wn * 64 + nf * 16 + fr;
        float bv = (MODE <= 1) ? bias[colg] : 0.f;
#pragma unroll
        for (int mf = 0; mf < 4; ++mf) {
            int rowbase = m0 + wm * 64 + mf * 16 + fg * 4;
#pragma unroll
            for (int j = 0; j < 4; ++j) {
                int rowg = rowbase + j;
                if (rowg < M) {
                    float v = acc[mf][nf][j] + bv;
                    size_t idx = (size_t)rowg * ldc + colg;
                    if (MODE >= 2) v += C[idx];
                    if (MODE & 1) v = fmaxf(v, 0.f);
                    if (OUTSPLIT) {
                        short hb, lb;
                        f2bf_split(v, hb, lb);
                        Ch[idx] = hb;
                        Cl[idx] = lb;
                    } else {
                        C[idx] = v;
                    }
                }
            }
        }
    }
}

template <int MODE, bool OSPL>
static void launch_gemm(const short* Agh, const short* Agl, int lda, long hopStride,
                        const short* BTh, const short* BTl, int ldb, int Kd,
                        float* C, short* Ch, short* Cl, int ldc,
                        const float* bias, int M, hipStream_t s) {
    dim3 grid(2, (M + 127) / 128);
    gemm_split<MODE, OSPL><<<grid, 256, 0, s>>>(Agh, Agl, lda, hopStride, BTh, BTl,
                                                ldb, Kd, C, Ch, Cl, ldc, bias, M);
}

// ---------------- driver ----------------

extern "C" void kernel_launch(void* const* d_in, const int* in_sizes, int n_in,
                              void* d_out, int out_size, void* d_ws, size_t ws_size,
                              hipStream_t stream) {
    const float* features = (const float*)d_in[0];
    const float* W1 = (const float*)d_in[1];
    const float* b1 = (const float*)d_in[2];
    const float* W2 = (const float*)d_in[3];
    const float* b2 = (const float*)d_in[4];
    const float* Wr = (const float*)d_in[5];
    const float* br = (const float*)d_in[6];
    const int* row = (const int*)d_in[7];
    const int* col = (const int*)d_in[8];
    float* out = (float*)d_out;

    // workspace layout (byte offsets; ws_size ~1953 MiB)
    char* ws = (char*)d_ws;
    int* deg = (int*)ws;                                 // 400KB (also cursor)
    int* rowptr = (int*)(ws + (1ull << 20));
    float* dinv = (float*)(ws + (2ull << 20));
    int* cols2 = (int*)(ws + (4ull << 20));              // 6.4MB
    float* ew = (float*)(ws + (11ull << 20));            // 6.4MB
    short* w1h = (short*)(ws + (18ull << 20));           // 459KB
    short* w1l = (short*)(ws + (19ull << 20));
    float* wc32 = (float*)(ws + (20ull << 20));          // 3.93MB
    short* wch = (short*)(ws + (24ull << 20));           // 1.97MB
    short* wcl = (short*)(ws + (26ull << 20));
    float* bc = (float*)(ws + (28ull << 20));            // 5KB
    float* xa = (float*)(ws + (32ull << 20));            // 51.2MB
    float* xb = (float*)(ws + (96ull << 20));            // 51.2MB
    short* xh = (short*)(ws + (160ull << 20));           // 25.6MB
    short* xl = (short*)(ws + (192ull << 20));           // 25.6MB
    short* h1h = (short*)(ws + (224ull << 20));          // windowed: 341.8MiB
    short* h1l = (short*)(ws + (576ull << 20));          // windowed: 341.8MiB

    const bool windowed = ws_size >= (1000ull << 20);

    // ---- adjacency normalization + CSR build ----
    zero_int<<<(N_NODES + 255) / 256, 256, 0, stream>>>(deg, N_NODES);
    deg_count<<<(E_EDGES + 255) / 256, 256, 0, stream>>>(row, deg);
    dinv_compute<<<(N_NODES + 255) / 256, 256, 0, stream>>>(deg, dinv);
    exscan_rowptr<<<1, 1024, 0, stream>>>(deg, rowptr);
    zero_int<<<(N_NODES + 255) / 256, 256, 0, stream>>>(deg, N_NODES);
    csr_scatter<<<(E_EDGES + 255) / 256, 256, 0, stream>>>(row, col, dinv, rowptr,
                                                           deg, cols2, ew);

    // ---- weight fusion: Wc = W2 @ WrS, bc = br + b2 @ WrS ----
    wc_compute<<<dim3(15, H_F), 256, 0, stream>>>(W2, Wr, wc32);
    bc_compute<<<R_REL, 256, 0, stream>>>(b2, Wr, br, bc);

    // ---- weight transpose + bf16 split ----
    dim3 tb(32, 8);
    transpose_convert<<<dim3(IN_F / 32, 8, K_HOPS), tb, 0, stream>>>(W1, w1h, w1l, IN_F, 1);
    transpose_convert<<<dim3(H_F / 32, 8, 15), tb, 0, stream>>>(wc32, wch, wcl, H_F, 3);

    // ---- split features for hop-0 MLP1 ----
    {
        int n4 = N_NODES * IN_F / 4;
        split_pack<<<(n4 + 255) / 256, 256, 0, stream>>>(
            (const float4*)features, (int2*)xh, (int2*)xl, n4);
    }

    // ---- hop loop: MLP1 only; then propagate ----
    const float* xcur = features;
    float* bufs[2] = {xa, xb};
    for (int k = 0; k < K_HOPS; ++k) {
        short* h1hd = windowed ? (h1h + (size_t)k * N_NODES * H_F) : h1h;
        short* h1ld = windowed ? (h1l + (size_t)k * N_NODES * H_F) : h1l;
        launch_gemm<1, true>(xh, xl, IN_F, 0,
                             w1h + (size_t)k * 256 * IN_F, w1l + (size_t)k * 256 * IN_F,
                             IN_F, IN_F, nullptr, h1hd, h1ld, H_F,
                             b1 + (size_t)k * H_F, N_NODES, stream);

        if (!windowed) {
            int rlo = (k - 2 < 0) ? 0 : (k - 2);
            int rhi = (k < R_REL - 1) ? k : (R_REL - 1);
            for (int r = rlo; r <= rhi; ++r) {
                int d = k - r;
                const short* Bh = wch + (size_t)r * 256 * 768 + (size_t)d * H_F;
                const short* Bl = wcl + (size_t)r * 256 * 768 + (size_t)d * H_F;
                float* Cp = out + (size_t)r * H_F;
                if (k == r)
                    launch_gemm<0, false>(h1h, h1l, H_F, 0, Bh, Bl, 768, H_F,
                                          Cp, nullptr, nullptr, OUT_W,
                                          bc + (size_t)r * H_F, N_NODES, stream);
                else if (k == r + 2)
                    launch_gemm<3, false>(h1h, h1l, H_F, 0, Bh, Bl, 768, H_F,
                                          Cp, nullptr, nullptr, OUT_W,
                                          nullptr, N_NODES, stream);
                else
                    launch_gemm<2, false>(h1h, h1l, H_F, 0, Bh, Bl, 768, H_F,
                                          Cp, nullptr, nullptr, OUT_W,
                                          nullptr, N_NODES, stream);
            }
        }

        if (k < K_HOPS - 1) {
            float* xn = bufs[k & 1];
            spmm_csr<<<(N_NODES + 3) / 4, 256, 0, stream>>>(
                (const float2*)xcur, rowptr, cols2, ew, dinv, (float2*)xn,
                (int*)xh, (int*)xl);
            xcur = xn;
        }
    }

    if (windowed) {
        // 5 relation GEMMs, K=768 over the h1 hop window (pre-split A)
        for (int r = 0; r < R_REL; ++r) {
            launch_gemm<1, false>(h1h + (size_t)r * N_NODES * H_F,
                                  h1l + (size_t)r * N_NODES * H_F, H_F,
                                  (long)N_NODES * H_F,
                                  wch + (size_t)r * 256 * 768, wcl + (size_t)r * 256 * 768,
                                  768, 768, out + (size_t)r * H_F, nullptr, nullptr, OUT_W,
                                  bc + (size_t)r * H_F, N_NODES, stream);
        }
    }
}

// Round 6
// 2437.400 us; speedup vs baseline: 1.1270x; 1.1270x over previous
//
#include <hip/hip_runtime.h>

#define N_NODES 100000
#define E_EDGES 1600000
#define IN_F 128
#define H_F 256
#define K_HOPS 7
#define R_REL 5
#define OUT_W (R_REL * H_F)  // 1280

typedef __attribute__((ext_vector_type(8))) short short8;
typedef __attribute__((ext_vector_type(4))) float f32x4;

// async global->LDS, 16B per lane; lds dest = base + lane*16
#define GLOAD16(g, l) __builtin_amdgcn_global_load_lds( \
    (const __attribute__((address_space(1))) void*)(g), \
    (__attribute__((address_space(3))) void*)(l), 16, 0, 0)

// ---------------- small utility kernels ----------------

__global__ void zero_int(int* __restrict__ p, int n) {
    int t = blockIdx.x * blockDim.x + threadIdx.x;
    if (t < n) p[t] = 0;
}

__global__ void deg_count(const int* __restrict__ row, int* __restrict__ deg) {
    int e = blockIdx.x * blockDim.x + threadIdx.x;
    if (e < E_EDGES) atomicAdd(&deg[row[e]], 1);
}

__global__ void dinv_compute(const int* __restrict__ deg, float* __restrict__ dinv) {
    int i = blockIdx.x * blockDim.x + threadIdx.x;
    if (i < N_NODES) dinv[i] = rsqrtf((float)(deg[i] + 1));
}

// exclusive scan of deg[N] -> rowptr[N+1], single 1024-thread block
__global__ __launch_bounds__(1024) void exscan_rowptr(const int* __restrict__ deg,
                                                      int* __restrict__ rowptr) {
    __shared__ int wsum[16];
    __shared__ int carry_s;
    const int t = threadIdx.x, lane = t & 63, wv = t >> 6;
    if (t == 0) carry_s = 0;
    __syncthreads();
    for (int base = 0; base < N_NODES; base += 1024) {
        int i = base + t;
        int v = (i < N_NODES) ? deg[i] : 0;
        int x = v;
#pragma unroll
        for (int off = 1; off < 64; off <<= 1) {
            int n = __shfl_up(x, off, 64);
            if (lane >= off) x += n;
        }
        if (lane == 63) wsum[wv] = x;
        __syncthreads();
        if (wv == 0 && lane < 16) {
            int s = wsum[lane];
#pragma unroll
            for (int off = 1; off < 16; off <<= 1) {
                int n = __shfl_up(s, off, 64);
                if (lane >= off) s += n;
            }
            wsum[lane] = s;
        }
        __syncthreads();
        int wbase = (wv == 0) ? 0 : wsum[wv - 1];
        if (i < N_NODES) rowptr[i] = carry_s + wbase + x - v;
        __syncthreads();
        if (t == 1023) carry_s += wsum[15];
        __syncthreads();
    }
    if (threadIdx.x == 0) rowptr[N_NODES] = carry_s;
}

__global__ void csr_scatter(const int* __restrict__ row, const int* __restrict__ col,
                            const float* __restrict__ dinv, const int* __restrict__ rowptr,
                            int* __restrict__ cursor, int* __restrict__ cols2,
                            float* __restrict__ ew) {
    int e = blockIdx.x * blockDim.x + threadIdx.x;
    if (e >= E_EDGES) return;
    int r = row[e], c = col[e];
    int pos = rowptr[r] + atomicAdd(&cursor[r], 1);
    cols2[pos] = c;
    ew[pos] = dinv[r] * dinv[c];
}

// y[i] = dinv[i]^2 * x[i] + sum_j w[j] * x[cols[j]]   (one wave per row, float2/lane)
__global__ __launch_bounds__(256) void spmm_csr(
    const float2* __restrict__ x, const int* __restrict__ rowptr,
    const int* __restrict__ cols, const float* __restrict__ w,
    const float* __restrict__ dinv, float2* __restrict__ y) {
    const int wave = threadIdx.x >> 6, lane = threadIdx.x & 63;
    const int i = blockIdx.x * 4 + wave;
    if (i >= N_NODES) return;
    const float d = dinv[i];
    float2 xv = x[(size_t)i * 64 + lane];
    float2 acc;
    acc.x = d * d * xv.x;
    acc.y = d * d * xv.y;
    int j = rowptr[i];
    const int e = rowptr[i + 1];
    for (; j + 3 < e; j += 4) {
        int c0 = cols[j], c1 = cols[j + 1], c2 = cols[j + 2], c3 = cols[j + 3];
        float w0 = w[j], w1 = w[j + 1], w2 = w[j + 2], w3 = w[j + 3];
        float2 v0 = x[(size_t)c0 * 64 + lane];
        float2 v1 = x[(size_t)c1 * 64 + lane];
        float2 v2 = x[(size_t)c2 * 64 + lane];
        float2 v3 = x[(size_t)c3 * 64 + lane];
        acc.x += w0 * v0.x + w1 * v1.x + w2 * v2.x + w3 * v3.x;
        acc.y += w0 * v0.y + w1 * v1.y + w2 * v2.y + w3 * v3.y;
    }
    for (; j < e; ++j) {
        int c0 = cols[j];
        float w0 = w[j];
        float2 v0 = x[(size_t)c0 * 64 + lane];
        acc.x += w0 * v0.x;
        acc.y += w0 * v0.y;
    }
    y[(size_t)i * 64 + lane] = acc;
}

// ---------------- bf16 split helpers ----------------

__device__ __forceinline__ void f2bf_split(float v, short& h, short& l) {
    unsigned u = __float_as_uint(v);
    unsigned hb = (u + 0x7FFFu + ((u >> 16) & 1u)) >> 16;  // RN-to-even bf16
    float fh = __uint_as_float(hb << 16);
    float r = v - fh;
    unsigned u2 = __float_as_uint(r);
    unsigned lb = (u2 + 0x7FFFu + ((u2 >> 16) & 1u)) >> 16;
    h = (short)(unsigned short)hb;
    l = (short)(unsigned short)lb;
}

// ---------------- weight-fusion precompute ----------------
// Wc[z=r*3+d] = W2[r+d] @ WrS[r,d]
__global__ __launch_bounds__(256) void wc_compute(const float* __restrict__ W2,
                                                  const float* __restrict__ Wr,
                                                  float* __restrict__ Wc) {
    const int z = blockIdx.x, j = blockIdx.y, g = threadIdx.x;
    const int r = z / 3, d = z % 3, hop = r + d;
    const float* a = W2 + (size_t)hop * H_F * H_F + (size_t)j * H_F;
    const float* b = Wr + ((size_t)r * 768 + (size_t)d * H_F) * H_F + g;
    float acc = 0.f;
#pragma unroll 4
    for (int h = 0; h < H_F; ++h) acc += a[h] * b[(size_t)h * H_F];
    Wc[(size_t)z * H_F * H_F + (size_t)j * H_F + g] = acc;
}

// bc[r] = br[r] + sum_{d,h} b2[r+d][h] * WrS[r,d][h][:]
__global__ __launch_bounds__(256) void bc_compute(const float* __restrict__ b2,
                                                  const float* __restrict__ Wr,
                                                  const float* __restrict__ br,
                                                  float* __restrict__ bc) {
    const int r = blockIdx.x, g = threadIdx.x;
    float acc = br[(size_t)r * H_F + g];
    for (int t = 0; t < 3 * H_F; ++t) {
        float bv = b2[(size_t)(r + t / H_F) * H_F + (t % H_F)];
        acc += bv * Wr[((size_t)r * 768 + t) * H_F + g];
    }
    bc[(size_t)r * H_F + g] = acc;
}

// weight transpose+split: in [z][Kd][256] fp32 -> out group (z/grp) is [256][grp*Kd]
__global__ void transpose_convert(const float* __restrict__ in, short* __restrict__ oh,
                                  short* __restrict__ ol, int Kd, int grp) {
    __shared__ float t[32][33];
    const int i0 = blockIdx.x * 32, n0 = blockIdx.y * 32, z = blockIdx.z;
    const int tx = threadIdx.x, ty = threadIdx.y;
    const int outLd = grp * Kd;
    const float* ip = in + (size_t)z * Kd * 256;
#pragma unroll
    for (int j = 0; j < 4; ++j)
        t[ty + 8 * j][tx] = ip[(size_t)(i0 + ty + 8 * j) * 256 + n0 + tx];
    __syncthreads();
    size_t base = (size_t)(z / grp) * 256 * outLd + (size_t)(z % grp) * Kd;
#pragma unroll
    for (int j = 0; j < 4; ++j) {
        float v = t[tx][ty + 8 * j];
        short hb, lb;
        f2bf_split(v, hb, lb);
        size_t o = base + (size_t)(n0 + ty + 8 * j) * outLd + i0 + tx;
        oh[o] = hb;
        ol[o] = lb;
    }
}

// ---------------- MLP1 GEMM: fp32 A, in-kernel split, split-bf16 output ----------------
// Ch/Cl[M,256] = relu(A[M,128] @ B[128,256] + bias), reg-staged, LROW=40 pad

#define LROW 40

__global__ __launch_bounds__(256, 2) void gemm_mlp(
    const float* __restrict__ A,
    const short* __restrict__ BTh, const short* __restrict__ BTl,
    short* __restrict__ Ch, short* __restrict__ Cl,
    const float* __restrict__ bias, int M)
{
    __shared__ short lds_buf[4 * 128 * LROW];
    short* Ah = lds_buf;
    short* Al = lds_buf + 128 * LROW;
    short* Bh = lds_buf + 2 * 128 * LROW;
    short* Bl = lds_buf + 3 * 128 * LROW;

    const int tid = threadIdx.x;
    const int lane = tid & 63, wave = tid >> 6;
    const int wm = wave & 1, wn = wave >> 1;
    const int fr = lane & 15, fg = lane >> 4;
    const int m0 = blockIdx.y * 128;
    const int n0 = blockIdx.x * 128;

    const int sr = tid >> 1;
    const int sc = (tid & 1) * 16;
    const bool avalid = (m0 + sr) < M;
    const int arow = avalid ? (m0 + sr) : (M - 1);

    f32x4 ga[4];
    short8 gbh[2], gbl[2];
    {
        const float* ap = A + (size_t)arow * IN_F + sc;
        const short* bph = BTh + (size_t)(n0 + sr) * IN_F + sc;
        const short* bpl = BTl + (size_t)(n0 + sr) * IN_F + sc;
#pragma unroll
        for (int l = 0; l < 4; ++l) ga[l] = *(const f32x4*)(ap + 4 * l);
        gbh[0] = *(const short8*)bph;  gbh[1] = *(const short8*)(bph + 8);
        gbl[0] = *(const short8*)bpl;  gbl[1] = *(const short8*)(bpl + 8);
    }

    f32x4 acc[4][4];
#pragma unroll
    for (int i = 0; i < 4; ++i)
#pragma unroll
        for (int j = 0; j < 4; ++j) acc[i][j] = (f32x4)0.f;

    const int nk = IN_F / 32;  // 4
    for (int kk = 0; kk < nk; ++kk) {
        __syncthreads();
        {
            short8 vh[2], vl[2];
#pragma unroll
            for (int l = 0; l < 4; ++l) {
                f32x4 v = ga[l];
                if (!avalid) v = (f32x4)0.f;
#pragma unroll
                for (int e = 0; e < 4; ++e) {
                    short hb, lb;
                    f2bf_split(v[e], hb, lb);
                    vh[l >> 1][(l & 1) * 4 + e] = hb;
                    vl[l >> 1][(l & 1) * 4 + e] = lb;
                }
            }
            *(short8*)(Ah + sr * LROW + sc)     = vh[0];
            *(short8*)(Ah + sr * LROW + sc + 8) = vh[1];
            *(short8*)(Al + sr * LROW + sc)     = vl[0];
            *(short8*)(Al + sr * LROW + sc + 8) = vl[1];
            *(short8*)(Bh + sr * LROW + sc)     = gbh[0];
            *(short8*)(Bh + sr * LROW + sc + 8) = gbh[1];
            *(short8*)(Bl + sr * LROW + sc)     = gbl[0];
            *(short8*)(Bl + sr * LROW + sc + 8) = gbl[1];
        }
        __syncthreads();

        if (kk + 1 < nk) {
            int k0 = (kk + 1) * 32;
            const float* ap = A + (size_t)arow * IN_F + k0 + sc;
            const short* bph = BTh + (size_t)(n0 + sr) * IN_F + k0 + sc;
            const short* bpl = BTl + (size_t)(n0 + sr) * IN_F + k0 + sc;
#pragma unroll
            for (int l = 0; l < 4; ++l) ga[l] = *(const f32x4*)(ap + 4 * l);
            gbh[0] = *(const short8*)bph;  gbh[1] = *(const short8*)(bph + 8);
            gbl[0] = *(const short8*)bpl;  gbl[1] = *(const short8*)(bpl + 8);
        }

        short8 afh[4], afl[4], bfh[4], bfl[4];
#pragma unroll
        for (int mf = 0; mf < 4; ++mf) {
            int r = wm * 64 + mf * 16 + fr;
            afh[mf] = *(const short8*)(Ah + r * LROW + fg * 8);
            afl[mf] = *(const short8*)(Al + r * LROW + fg * 8);
        }
#pragma unroll
        for (int nf = 0; nf < 4; ++nf) {
            int r = wn * 64 + nf * 16 + fr;
            bfh[nf] = *(const short8*)(Bh + r * LROW + fg * 8);
            bfl[nf] = *(const short8*)(Bl + r * LROW + fg * 8);
        }
#pragma unroll
        for (int mf = 0; mf < 4; ++mf)
#pragma unroll
            for (int nf = 0; nf < 4; ++nf) {
                acc[mf][nf] = __builtin_amdgcn_mfma_f32_16x16x32_bf16(
                    afh[mf], bfh[nf], acc[mf][nf], 0, 0, 0);
                acc[mf][nf] = __builtin_amdgcn_mfma_f32_16x16x32_bf16(
                    afh[mf], bfl[nf], acc[mf][nf], 0, 0, 0);
                acc[mf][nf] = __builtin_amdgcn_mfma_f32_16x16x32_bf16(
                    afl[mf], bfh[nf], acc[mf][nf], 0, 0, 0);
            }
    }

#pragma unroll
    for (int nf = 0; nf < 4; ++nf) {
        int colg = n0 + wn * 64 + nf * 16 + fr;
        float bv = bias[colg];
#pragma unroll
        for (int mf = 0; mf < 4; ++mf) {
            int rowbase = m0 + wm * 64 + mf * 16 + fg * 4;
#pragma unroll
            for (int j = 0; j < 4; ++j) {
                int rowg = rowbase + j;
                if (rowg < M) {
                    float v = fmaxf(acc[mf][nf][j] + bv, 0.f);
                    short hb, lb;
                    f2bf_split(v, hb, lb);
                    size_t idx = (size_t)rowg * H_F + colg;
                    Ch[idx] = hb;
                    Cl[idx] = lb;
                }
            }
        }
    }
}

// ---------------- relation GEMM: gload_lds DMA staging, dbuf, 1 barrier/K-step ----
// out[:, r*256 + n] = relu( sum_k h1[hop(r,k)][m][k%256] * Wc[r][k][n] + bc[r][n] )
// K = 768, BK = 32; LDS tiles [128][32] shorts, swizzled: 16B unit u of row r holds
// global unit (u - (r>>1)) & 3; read back at u = (fg + (r>>1)) & 3 -> 2-way banks.

__global__ __launch_bounds__(256, 2) void gemm_rel(
    const short* __restrict__ h1h, const short* __restrict__ h1l, long hopStride,
    const short* __restrict__ wch, const short* __restrict__ wcl,
    float* __restrict__ outB, const float* __restrict__ bcB, int M)
{
    __shared__ short lds[2][4][128 * 32];

    const int tid = threadIdx.x;
    const int lane = tid & 63, wave = tid >> 6;
    const int wm = wave & 1, wn = wave >> 1;
    const int fr = lane & 15, fg = lane >> 4;
    const int m0 = blockIdx.y * 128;
    const int n0 = blockIdx.x * 128;
    const int rrel = blockIdx.z;

    const short* Agh = h1h + (size_t)rrel * hopStride;
    const short* Agl = h1l + (size_t)rrel * hopStride;
    const short* BTh = wch + (size_t)rrel * 256 * 768;
    const short* BTl = wcl + (size_t)rrel * 256 * 768;
    float* C = outB + (size_t)rrel * H_F;
    const float* bias = bcB + (size_t)rrel * H_F;

    // staging offsets (2 DMA calls per buffer per wave; call c covers rows c*16..c*16+15)
    int aoff[2], boff[2], loff[2];
#pragma unroll
    for (int q = 0; q < 2; ++q) {
        int c = wave * 2 + q;
        int r = c * 16 + (lane >> 2);
        int u = lane & 3;
        int g = (u - (r >> 1)) & 3;
        int ar = m0 + r; if (ar >= M) ar = M - 1;
        aoff[q] = ar * H_F + g * 8;        // A row stride 256 shorts
        boff[q] = (n0 + r) * 768 + g * 8;  // B row stride 768 shorts
        loff[q] = c * 512;                 // 1KB per call
    }

#define STAGE_REL(buf, kg) do {                                                  \
        int hop_ = (kg) >> 8, kin_ = (kg) & 255;                                 \
        const short* ah_ = Agh + (size_t)hop_ * hopStride + kin_;                \
        const short* al_ = Agl + (size_t)hop_ * hopStride + kin_;                \
        const short* bh_ = BTh + (kg);                                           \
        const short* bl_ = BTl + (kg);                                           \
        GLOAD16(ah_ + aoff[0], &lds[buf][0][loff[0]]);                           \
        GLOAD16(ah_ + aoff[1], &lds[buf][0][loff[1]]);                           \
        GLOAD16(al_ + aoff[0], &lds[buf][1][loff[0]]);                           \
        GLOAD16(al_ + aoff[1], &lds[buf][1][loff[1]]);                           \
        GLOAD16(bh_ + boff[0], &lds[buf][2][loff[0]]);                           \
        GLOAD16(bh_ + boff[1], &lds[buf][2][loff[1]]);                           \
        GLOAD16(bl_ + boff[0], &lds[buf][3][loff[0]]);                           \
        GLOAD16(bl_ + boff[1], &lds[buf][3][loff[1]]);                           \
    } while (0)

    f32x4 acc[4][4];
#pragma unroll
    for (int i = 0; i < 4; ++i)
#pragma unroll
        for (int j = 0; j < 4; ++j) acc[i][j] = (f32x4)0.f;

    STAGE_REL(0, 0);
    __syncthreads();  // drains vmcnt before first reads

    int cur = 0;
    const int nk = 768 / 32;  // 24
    for (int kt = 0; kt < nk; ++kt) {
        if (kt + 1 < nk) STAGE_REL(cur ^ 1, (kt + 1) * 32);

        const short* Ahc = &lds[cur][0][0];
        const short* Alc = &lds[cur][1][0];
        const short* Bhc = &lds[cur][2][0];
        const short* Blc = &lds[cur][3][0];

        short8 bfh[4], bfl[4];
#pragma unroll
        for (int nf = 0; nf < 4; ++nf) {
            int rb = wn * 64 + nf * 16 + fr;
            int ub = (fg + (rb >> 1)) & 3;
            bfh[nf] = *(const short8*)(Bhc + rb * 32 + ub * 8);
            bfl[nf] = *(const short8*)(Blc + rb * 32 + ub * 8);
        }
#pragma unroll
        for (int mf = 0; mf < 4; ++mf) {
            int ra = wm * 64 + mf * 16 + fr;
            int ua = (fg + (ra >> 1)) & 3;
            short8 ah = *(const short8*)(Ahc + ra * 32 + ua * 8);
            short8 al = *(const short8*)(Alc + ra * 32 + ua * 8);
#pragma unroll
            for (int nf = 0; nf < 4; ++nf) {
                acc[mf][nf] = __builtin_amdgcn_mfma_f32_16x16x32_bf16(
                    ah, bfh[nf], acc[mf][nf], 0, 0, 0);
                acc[mf][nf] = __builtin_amdgcn_mfma_f32_16x16x32_bf16(
                    ah, bfl[nf], acc[mf][nf], 0, 0, 0);
                acc[mf][nf] = __builtin_amdgcn_mfma_f32_16x16x32_bf16(
                    al, bfh[nf], acc[mf][nf], 0, 0, 0);
            }
        }
        __syncthreads();  // implicit vmcnt(0)+lgkmcnt(0) drain: next-stage landed, reads done
        cur ^= 1;
    }

#pragma unroll
    for (int nf = 0; nf < 4; ++nf) {
        int colg = n0 + wn * 64 + nf * 16 + fr;
        float bv = bias[colg];
#pragma unroll
        for (int mf = 0; mf < 4; ++mf) {
            int rowbase = m0 + wm * 64 + mf * 16 + fg * 4;
#pragma unroll
            for (int j = 0; j < 4; ++j) {
                int rowg = rowbase + j;
                if (rowg < M)
                    C[(size_t)rowg * OUT_W + colg] = fmaxf(acc[mf][nf][j] + bv, 0.f);
            }
        }
    }
#undef STAGE_REL
}

// ---------------- fallback relation GEMM (pre-split A, reg-staged) ----------------
// MODE: 0 = bias, 2 = accum, 3 = accum+relu   (non-windowed path only)

template <int MODE>
__global__ __launch_bounds__(256, 2) void gemm_presplit(
    const short* __restrict__ Agh, const short* __restrict__ Agl, int lda,
    const short* __restrict__ BTh, const short* __restrict__ BTl, int ldb, int Kd,
    float* __restrict__ C, int ldc, const float* __restrict__ bias, int M)
{
    __shared__ short lds_buf[4 * 128 * LROW];
    short* Ah = lds_buf;
    short* Al = lds_buf + 128 * LROW;
    short* Bh = lds_buf + 2 * 128 * LROW;
    short* Bl = lds_buf + 3 * 128 * LROW;

    const int tid = threadIdx.x;
    const int lane = tid & 63, wave = tid >> 6;
    const int wm = wave & 1, wn = wave >> 1;
    const int fr = lane & 15, fg = lane >> 4;
    const int m0 = blockIdx.y * 128;
    const int n0 = blockIdx.x * 128;

    const int sr = tid >> 1;
    const int sc = (tid & 1) * 16;
    const bool avalid = (m0 + sr) < M;
    const int arow = avalid ? (m0 + sr) : (M - 1);

    short8 gah[2], gal[2], gbh[2], gbl[2];
    {
        const short* aph = Agh + (size_t)arow * lda + sc;
        const short* apl = Agl + (size_t)arow * lda + sc;
        const short* bph = BTh + (size_t)(n0 + sr) * ldb + sc;
        const short* bpl = BTl + (size_t)(n0 + sr) * ldb + sc;
        gah[0] = *(const short8*)aph;  gah[1] = *(const short8*)(aph + 8);
        gal[0] = *(const short8*)apl;  gal[1] = *(const short8*)(apl + 8);
        gbh[0] = *(const short8*)bph;  gbh[1] = *(const short8*)(bph + 8);
        gbl[0] = *(const short8*)bpl;  gbl[1] = *(const short8*)(bpl + 8);
    }

    f32x4 acc[4][4];
#pragma unroll
    for (int i = 0; i < 4; ++i)
#pragma unroll
        for (int j = 0; j < 4; ++j) acc[i][j] = (f32x4)0.f;

    const int nk = Kd / 32;
    for (int kk = 0; kk < nk; ++kk) {
        __syncthreads();
        *(short8*)(Ah + sr * LROW + sc)     = gah[0];
        *(short8*)(Ah + sr * LROW + sc + 8) = gah[1];
        *(short8*)(Al + sr * LROW + sc)     = gal[0];
        *(short8*)(Al + sr * LROW + sc + 8) = gal[1];
        *(short8*)(Bh + sr * LROW + sc)     = gbh[0];
        *(short8*)(Bh + sr * LROW + sc + 8) = gbh[1];
        *(short8*)(Bl + sr * LROW + sc)     = gbl[0];
        *(short8*)(Bl + sr * LROW + sc + 8) = gbl[1];
        __syncthreads();

        if (kk + 1 < nk) {
            int k0 = (kk + 1) * 32;
            const short* aph = Agh + (size_t)arow * lda + k0 + sc;
            const short* apl = Agl + (size_t)arow * lda + k0 + sc;
            const short* bph = BTh + (size_t)(n0 + sr) * ldb + k0 + sc;
            const short* bpl = BTl + (size_t)(n0 + sr) * ldb + k0 + sc;
            gah[0] = *(const short8*)aph;  gah[1] = *(const short8*)(aph + 8);
            gal[0] = *(const short8*)apl;  gal[1] = *(const short8*)(apl + 8);
            gbh[0] = *(const short8*)bph;  gbh[1] = *(const short8*)(bph + 8);
            gbl[0] = *(const short8*)bpl;  gbl[1] = *(const short8*)(bpl + 8);
        }

        short8 afh[4], afl[4], bfh[4], bfl[4];
#pragma unroll
        for (int mf = 0; mf < 4; ++mf) {
            int r = wm * 64 + mf * 16 + fr;
            afh[mf] = *(const short8*)(Ah + r * LROW + fg * 8);
            afl[mf] = *(const short8*)(Al + r * LROW + fg * 8);
        }
#pragma unroll
        for (int nf = 0; nf < 4; ++nf) {
            int r = wn * 64 + nf * 16 + fr;
            bfh[nf] = *(const short8*)(Bh + r * LROW + fg * 8);
            bfl[nf] = *(const short8*)(Bl + r * LROW + fg * 8);
        }
#pragma unroll
        for (int mf = 0; mf < 4; ++mf)
#pragma unroll
            for (int nf = 0; nf < 4; ++nf) {
                acc[mf][nf] = __builtin_amdgcn_mfma_f32_16x16x32_bf16(
                    afh[mf], bfh[nf], acc[mf][nf], 0, 0, 0);
                acc[mf][nf] = __builtin_amdgcn_mfma_f32_16x16x32_bf16(
                    afh[mf], bfl[nf], acc[mf][nf], 0, 0, 0);
                acc[mf][nf] = __builtin_amdgcn_mfma_f32_16x16x32_bf16(
                    afl[mf], bfh[nf], acc[mf][nf], 0, 0, 0);
            }
    }

#pragma unroll
    for (int nf = 0; nf < 4; ++nf) {
        int colg = n0 + wn * 64 + nf * 16 + fr;
        float bv = (MODE == 0) ? bias[colg] : 0.f;
#pragma unroll
        for (int mf = 0; mf < 4; ++mf) {
            int rowbase = m0 + wm * 64 + mf * 16 + fg * 4;
#pragma unroll
            for (int j = 0; j < 4; ++j) {
                int rowg = rowbase + j;
                if (rowg < M) {
                    size_t idx = (size_t)rowg * ldc + colg;
                    float v = acc[mf][nf][j] + bv;
                    if (MODE >= 2) v += C[idx];
                    if (MODE & 1) v = fmaxf(v, 0.f);
                    C[idx] = v;
                }
            }
        }
    }
}

// ---------------- driver ----------------

extern "C" void kernel_launch(void* const* d_in, const int* in_sizes, int n_in,
                              void* d_out, int out_size, void* d_ws, size_t ws_size,
                              hipStream_t stream) {
    const float* features = (const float*)d_in[0];
    const float* W1 = (const float*)d_in[1];
    const float* b1 = (const float*)d_in[2];
    const float* W2 = (const float*)d_in[3];
    const float* b2 = (const float*)d_in[4];
    const float* Wr = (const float*)d_in[5];
    const float* br = (const float*)d_in[6];
    const int* row = (const int*)d_in[7];
    const int* col = (const int*)d_in[8];
    float* out = (float*)d_out;

    // workspace layout (byte offsets; ws_size ~1953 MiB)
    char* ws = (char*)d_ws;
    int* deg = (int*)ws;                                 // 400KB (also cursor)
    int* rowptr = (int*)(ws + (1ull << 20));
    float* dinv = (float*)(ws + (2ull << 20));
    int* cols2 = (int*)(ws + (4ull << 20));              // 6.4MB
    float* ew = (float*)(ws + (11ull << 20));            // 6.4MB
    short* w1h = (short*)(ws + (18ull << 20));           // 459KB
    short* w1l = (short*)(ws + (19ull << 20));
    float* wc32 = (float*)(ws + (20ull << 20));          // 3.93MB
    short* wch = (short*)(ws + (24ull << 20));           // 1.97MB
    short* wcl = (short*)(ws + (26ull << 20));
    float* bc = (float*)(ws + (28ull << 20));            // 5KB
    float* xa = (float*)(ws + (32ull << 20));            // 51.2MB
    float* xb = (float*)(ws + (96ull << 20));            // 51.2MB
    short* h1h = (short*)(ws + (160ull << 20));          // 341.8MiB (windowed)
    short* h1l = (short*)(ws + (576ull << 20));          // 341.8MiB

    const bool windowed = ws_size >= (1000ull << 20);

    // ---- adjacency normalization + CSR build ----
    zero_int<<<(N_NODES + 255) / 256, 256, 0, stream>>>(deg, N_NODES);
    deg_count<<<(E_EDGES + 255) / 256, 256, 0, stream>>>(row, deg);
    dinv_compute<<<(N_NODES + 255) / 256, 256, 0, stream>>>(deg, dinv);
    exscan_rowptr<<<1, 1024, 0, stream>>>(deg, rowptr);
    zero_int<<<(N_NODES + 255) / 256, 256, 0, stream>>>(deg, N_NODES);
    csr_scatter<<<(E_EDGES + 255) / 256, 256, 0, stream>>>(row, col, dinv, rowptr,
                                                           deg, cols2, ew);

    // ---- weight fusion: Wc = W2 @ WrS, bc = br + b2 @ WrS ----
    wc_compute<<<dim3(15, H_F), 256, 0, stream>>>(W2, Wr, wc32);
    bc_compute<<<R_REL, 256, 0, stream>>>(b2, Wr, br, bc);

    // ---- weight transpose + bf16 split ----
    dim3 tb(32, 8);
    transpose_convert<<<dim3(IN_F / 32, 8, K_HOPS), tb, 0, stream>>>(W1, w1h, w1l, IN_F, 1);
    transpose_convert<<<dim3(H_F / 32, 8, 15), tb, 0, stream>>>(wc32, wch, wcl, H_F, 3);

    // ---- hop loop: MLP1 (fp32 A in, split bf16 out); then propagate ----
    const float* xcur = features;
    float* bufs[2] = {xa, xb};
    for (int k = 0; k < K_HOPS; ++k) {
        short* h1hd = windowed ? (h1h + (size_t)k * N_NODES * H_F) : h1h;
        short* h1ld = windowed ? (h1l + (size_t)k * N_NODES * H_F) : h1l;
        dim3 grid(2, (N_NODES + 127) / 128);
        gemm_mlp<<<grid, 256, 0, stream>>>(xcur, w1h + (size_t)k * 256 * IN_F,
                                           w1l + (size_t)k * 256 * IN_F,
                                           h1hd, h1ld, b1 + (size_t)k * H_F, N_NODES);

        if (!windowed) {
            int rlo = (k - 2 < 0) ? 0 : (k - 2);
            int rhi = (k < R_REL - 1) ? k : (R_REL - 1);
            for (int r = rlo; r <= rhi; ++r) {
                int d = k - r;
                const short* Bh = wch + (size_t)r * 256 * 768 + (size_t)d * H_F;
                const short* Bl = wcl + (size_t)r * 256 * 768 + (size_t)d * H_F;
                float* Cp = out + (size_t)r * H_F;
                if (k == r)
                    gemm_presplit<0><<<grid, 256, 0, stream>>>(
                        h1h, h1l, H_F, Bh, Bl, 768, H_F, Cp, OUT_W,
                        bc + (size_t)r * H_F, N_NODES);
                else if (k == r + 2)
                    gemm_presplit<3><<<grid, 256, 0, stream>>>(
                        h1h, h1l, H_F, Bh, Bl, 768, H_F, Cp, OUT_W, nullptr, N_NODES);
                else
                    gemm_presplit<2><<<grid, 256, 0, stream>>>(
                        h1h, h1l, H_F, Bh, Bl, 768, H_F, Cp, OUT_W, nullptr, N_NODES);
            }
        }

        if (k < K_HOPS - 1) {
            float* xn = bufs[k & 1];
            spmm_csr<<<(N_NODES + 3) / 4, 256, 0, stream>>>(
                (const float2*)xcur, rowptr, cols2, ew, dinv, (float2*)xn);
            xcur = xn;
        }
    }

    if (windowed) {
        // all 5 relation GEMMs in one launch (grid.z = r), K=768 over h1 hop window
        dim3 grid(2, (N_NODES + 127) / 128, R_REL);
        gemm_rel<<<grid, 256, 0, stream>>>(h1h, h1l, (long)N_NODES * H_F,
                                           wch, wcl, out, bc, N_NODES);
    }
}

// Round 7
// 2331.135 us; speedup vs baseline: 1.1783x; 1.0456x over previous
//
#include <hip/hip_runtime.h>

#define N_NODES 100000
#define E_EDGES 1600000
#define IN_F 128
#define H_F 256
#define K_HOPS 7
#define R_REL 5
#define OUT_W (R_REL * H_F)  // 1280
#define SCAN_B ((N_NODES + 1023) / 1024)  // 98

typedef __attribute__((ext_vector_type(8))) short short8;
typedef __attribute__((ext_vector_type(4))) float f32x4;

// async global->LDS, 16B per lane; lds dest = base + lane*16
#define GLOAD16(g, l) __builtin_amdgcn_global_load_lds( \
    (const __attribute__((address_space(1))) void*)(g), \
    (__attribute__((address_space(3))) void*)(l), 16, 0, 0)

// ---------------- small utility kernels ----------------

__global__ void zero_int(int* __restrict__ p, int n) {
    int t = blockIdx.x * blockDim.x + threadIdx.x;
    if (t < n) p[t] = 0;
}

__global__ void deg_count(const int* __restrict__ row, int* __restrict__ deg) {
    int e = blockIdx.x * blockDim.x + threadIdx.x;
    if (e < E_EDGES) atomicAdd(&deg[row[e]], 1);
}

__global__ void dinv_compute(const int* __restrict__ deg, float* __restrict__ dinv) {
    int i = blockIdx.x * blockDim.x + threadIdx.x;
    if (i < N_NODES) dinv[i] = rsqrtf((float)(deg[i] + 1));
}

// ---- 3-pass exclusive scan of deg -> rowptr ----
__global__ __launch_bounds__(1024) void scan1(const int* __restrict__ deg,
                                              int* __restrict__ rp, int* __restrict__ bsum) {
    __shared__ int ws[16];
    const int t = threadIdx.x, lane = t & 63, wv = t >> 6;
    int i = blockIdx.x * 1024 + t;
    int v = (i < N_NODES) ? deg[i] : 0;
    int x = v;
#pragma unroll
    for (int off = 1; off < 64; off <<= 1) {
        int n = __shfl_up(x, off, 64);
        if (lane >= off) x += n;
    }
    if (lane == 63) ws[wv] = x;
    __syncthreads();
    if (wv == 0 && lane < 16) {
        int s = ws[lane];
#pragma unroll
        for (int off = 1; off < 16; off <<= 1) {
            int n = __shfl_up(s, off, 64);
            if (lane >= off) s += n;
        }
        ws[lane] = s;
    }
    __syncthreads();
    int wbase = (wv == 0) ? 0 : ws[wv - 1];
    if (i < N_NODES) rp[i] = wbase + x - v;
    if (t == 1023) bsum[blockIdx.x] = ws[15];
}

__global__ void scan2(int* __restrict__ bsum) {
    if (threadIdx.x == 0 && blockIdx.x == 0) {
        int acc = 0;
        for (int b = 0; b < SCAN_B; ++b) { int v = bsum[b]; bsum[b] = acc; acc += v; }
        bsum[SCAN_B] = acc;
    }
}

__global__ __launch_bounds__(1024) void scan3(int* __restrict__ rp,
                                              const int* __restrict__ bsum) {
    int i = blockIdx.x * 1024 + threadIdx.x;
    if (i < N_NODES) rp[i] += bsum[blockIdx.x];
    if (i == 0) rp[N_NODES] = bsum[SCAN_B];
}

__global__ void csr_scatter(const int* __restrict__ row, const int* __restrict__ col,
                            const float* __restrict__ dinv, const int* __restrict__ rowptr,
                            int* __restrict__ cursor, int* __restrict__ cols2,
                            float* __restrict__ ew) {
    int e = blockIdx.x * blockDim.x + threadIdx.x;
    if (e >= E_EDGES) return;
    int r = row[e], c = col[e];
    int pos = rowptr[r] + atomicAdd(&cursor[r], 1);
    cols2[pos] = c;
    ew[pos] = dinv[r] * dinv[c];
}

// y[i] = dinv[i]^2 * x[i] + sum_j w[j] * x[cols[j]]   (one wave per row, float2/lane)
__global__ __launch_bounds__(256) void spmm_csr(
    const float2* __restrict__ x, const int* __restrict__ rowptr,
    const int* __restrict__ cols, const float* __restrict__ w,
    const float* __restrict__ dinv, float2* __restrict__ y) {
    const int wave = threadIdx.x >> 6, lane = threadIdx.x & 63;
    const int i = blockIdx.x * 4 + wave;
    if (i >= N_NODES) return;
    const float d = dinv[i];
    float2 xv = x[(size_t)i * 64 + lane];
    float2 acc;
    acc.x = d * d * xv.x;
    acc.y = d * d * xv.y;
    int j = rowptr[i];
    const int e = rowptr[i + 1];
    for (; j + 3 < e; j += 4) {
        int c0 = cols[j], c1 = cols[j + 1], c2 = cols[j + 2], c3 = cols[j + 3];
        float w0 = w[j], w1 = w[j + 1], w2 = w[j + 2], w3 = w[j + 3];
        float2 v0 = x[(size_t)c0 * 64 + lane];
        float2 v1 = x[(size_t)c1 * 64 + lane];
        float2 v2 = x[(size_t)c2 * 64 + lane];
        float2 v3 = x[(size_t)c3 * 64 + lane];
        acc.x += w0 * v0.x + w1 * v1.x + w2 * v2.x + w3 * v3.x;
        acc.y += w0 * v0.y + w1 * v1.y + w2 * v2.y + w3 * v3.y;
    }
    for (; j < e; ++j) {
        int c0 = cols[j];
        float w0 = w[j];
        float2 v0 = x[(size_t)c0 * 64 + lane];
        acc.x += w0 * v0.x;
        acc.y += w0 * v0.y;
    }
    y[(size_t)i * 64 + lane] = acc;
}

// ---------------- bf16 split helpers ----------------

__device__ __forceinline__ void f2bf_split(float v, short& h, short& l) {
    unsigned u = __float_as_uint(v);
    unsigned hb = (u + 0x7FFFu + ((u >> 16) & 1u)) >> 16;  // RN-to-even bf16
    float fh = __uint_as_float(hb << 16);
    float r = v - fh;
    unsigned u2 = __float_as_uint(r);
    unsigned lb = (u2 + 0x7FFFu + ((u2 >> 16) & 1u)) >> 16;
    h = (short)(unsigned short)hb;
    l = (short)(unsigned short)lb;
}

// ---------------- weight-fusion precompute ----------------
// Wc[z=r*3+d] = W2[r+d] @ WrS[r,d]
__global__ __launch_bounds__(256) void wc_compute(const float* __restrict__ W2,
                                                  const float* __restrict__ Wr,
                                                  float* __restrict__ Wc) {
    const int z = blockIdx.x, j = blockIdx.y, g = threadIdx.x;
    const int r = z / 3, d = z % 3, hop = r + d;
    const float* a = W2 + (size_t)hop * H_F * H_F + (size_t)j * H_F;
    const float* b = Wr + ((size_t)r * 768 + (size_t)d * H_F) * H_F + g;
    float acc = 0.f;
#pragma unroll 4
    for (int h = 0; h < H_F; ++h) acc += a[h] * b[(size_t)h * H_F];
    Wc[(size_t)z * H_F * H_F + (size_t)j * H_F + g] = acc;
}

// bc[r] = br[r] + sum_{d,h} b2[r+d][h] * WrS[r,d][h][:]
__global__ __launch_bounds__(256) void bc_compute(const float* __restrict__ b2,
                                                  const float* __restrict__ Wr,
                                                  const float* __restrict__ br,
                                                  float* __restrict__ bc) {
    const int r = blockIdx.x, g = threadIdx.x;
    float acc = br[(size_t)r * H_F + g];
    for (int t = 0; t < 3 * H_F; ++t) {
        float bv = b2[(size_t)(r + t / H_F) * H_F + (t % H_F)];
        acc += bv * Wr[((size_t)r * 768 + t) * H_F + g];
    }
    bc[(size_t)r * H_F + g] = acc;
}

// weight transpose+split: in [z][Kd][256] fp32 -> out group (z/grp) is [256][grp*Kd]
__global__ void transpose_convert(const float* __restrict__ in, short* __restrict__ oh,
                                  short* __restrict__ ol, int Kd, int grp) {
    __shared__ float t[32][33];
    const int i0 = blockIdx.x * 32, n0 = blockIdx.y * 32, z = blockIdx.z;
    const int tx = threadIdx.x, ty = threadIdx.y;
    const int outLd = grp * Kd;
    const float* ip = in + (size_t)z * Kd * 256;
#pragma unroll
    for (int j = 0; j < 4; ++j)
        t[ty + 8 * j][tx] = ip[(size_t)(i0 + ty + 8 * j) * 256 + n0 + tx];
    __syncthreads();
    size_t base = (size_t)(z / grp) * 256 * outLd + (size_t)(z % grp) * Kd;
#pragma unroll
    for (int j = 0; j < 4; ++j) {
        float v = t[tx][ty + 8 * j];
        short hb, lb;
        f2bf_split(v, hb, lb);
        size_t o = base + (size_t)(n0 + ty + 8 * j) * outLd + i0 + tx;
        oh[o] = hb;
        ol[o] = lb;
    }
}

// ---------------- MLP1 GEMM: fp32 A, in-kernel split, split-bf16 output ----------------
// Ch/Cl[M,256] = relu(A[M,128] @ B[128,256] + bias), reg-staged, LROW=40 pad

#define LROW 40

__global__ __launch_bounds__(256, 2) void gemm_mlp(
    const float* __restrict__ A,
    const short* __restrict__ BTh, const short* __restrict__ BTl,
    short* __restrict__ Ch, short* __restrict__ Cl,
    const float* __restrict__ bias, int M)
{
    __shared__ short lds_buf[4 * 128 * LROW];
    short* Ah = lds_buf;
    short* Al = lds_buf + 128 * LROW;
    short* Bh = lds_buf + 2 * 128 * LROW;
    short* Bl = lds_buf + 3 * 128 * LROW;

    const int tid = threadIdx.x;
    const int lane = tid & 63, wave = tid >> 6;
    const int wm = wave & 1, wn = wave >> 1;
    const int fr = lane & 15, fg = lane >> 4;
    const int m0 = blockIdx.y * 128;
    const int n0 = blockIdx.x * 128;

    const int sr = tid >> 1;
    const int sc = (tid & 1) * 16;
    const bool avalid = (m0 + sr) < M;
    const int arow = avalid ? (m0 + sr) : (M - 1);

    f32x4 ga[4];
    short8 gbh[2], gbl[2];
    {
        const float* ap = A + (size_t)arow * IN_F + sc;
        const short* bph = BTh + (size_t)(n0 + sr) * IN_F + sc;
        const short* bpl = BTl + (size_t)(n0 + sr) * IN_F + sc;
#pragma unroll
        for (int l = 0; l < 4; ++l) ga[l] = *(const f32x4*)(ap + 4 * l);
        gbh[0] = *(const short8*)bph;  gbh[1] = *(const short8*)(bph + 8);
        gbl[0] = *(const short8*)bpl;  gbl[1] = *(const short8*)(bpl + 8);
    }

    f32x4 acc[4][4];
#pragma unroll
    for (int i = 0; i < 4; ++i)
#pragma unroll
        for (int j = 0; j < 4; ++j) acc[i][j] = (f32x4)0.f;

    const int nk = IN_F / 32;  // 4
    for (int kk = 0; kk < nk; ++kk) {
        __syncthreads();
        {
            short8 vh[2], vl[2];
#pragma unroll
            for (int l = 0; l < 4; ++l) {
                f32x4 v = ga[l];
                if (!avalid) v = (f32x4)0.f;
#pragma unroll
                for (int e = 0; e < 4; ++e) {
                    short hb, lb;
                    f2bf_split(v[e], hb, lb);
                    vh[l >> 1][(l & 1) * 4 + e] = hb;
                    vl[l >> 1][(l & 1) * 4 + e] = lb;
                }
            }
            *(short8*)(Ah + sr * LROW + sc)     = vh[0];
            *(short8*)(Ah + sr * LROW + sc + 8) = vh[1];
            *(short8*)(Al + sr * LROW + sc)     = vl[0];
            *(short8*)(Al + sr * LROW + sc + 8) = vl[1];
            *(short8*)(Bh + sr * LROW + sc)     = gbh[0];
            *(short8*)(Bh + sr * LROW + sc + 8) = gbh[1];
            *(short8*)(Bl + sr * LROW + sc)     = gbl[0];
            *(short8*)(Bl + sr * LROW + sc + 8) = gbl[1];
        }
        __syncthreads();

        if (kk + 1 < nk) {
            int k0 = (kk + 1) * 32;
            const float* ap = A + (size_t)arow * IN_F + k0 + sc;
            const short* bph = BTh + (size_t)(n0 + sr) * IN_F + k0 + sc;
            const short* bpl = BTl + (size_t)(n0 + sr) * IN_F + k0 + sc;
#pragma unroll
            for (int l = 0; l < 4; ++l) ga[l] = *(const f32x4*)(ap + 4 * l);
            gbh[0] = *(const short8*)(bph);  gbh[1] = *(const short8*)(bph + 8);
            gbl[0] = *(const short8*)(bpl);  gbl[1] = *(const short8*)(bpl + 8);
        }

        short8 afh[4], afl[4], bfh[4], bfl[4];
#pragma unroll
        for (int mf = 0; mf < 4; ++mf) {
            int r = wm * 64 + mf * 16 + fr;
            afh[mf] = *(const short8*)(Ah + r * LROW + fg * 8);
            afl[mf] = *(const short8*)(Al + r * LROW + fg * 8);
        }
#pragma unroll
        for (int nf = 0; nf < 4; ++nf) {
            int r = wn * 64 + nf * 16 + fr;
            bfh[nf] = *(const short8*)(Bh + r * LROW + fg * 8);
            bfl[nf] = *(const short8*)(Bl + r * LROW + fg * 8);
        }
#pragma unroll
        for (int mf = 0; mf < 4; ++mf)
#pragma unroll
            for (int nf = 0; nf < 4; ++nf) {
                acc[mf][nf] = __builtin_amdgcn_mfma_f32_16x16x32_bf16(
                    afh[mf], bfh[nf], acc[mf][nf], 0, 0, 0);
                acc[mf][nf] = __builtin_amdgcn_mfma_f32_16x16x32_bf16(
                    afh[mf], bfl[nf], acc[mf][nf], 0, 0, 0);
                acc[mf][nf] = __builtin_amdgcn_mfma_f32_16x16x32_bf16(
                    afl[mf], bfh[nf], acc[mf][nf], 0, 0, 0);
            }
    }

#pragma unroll
    for (int nf = 0; nf < 4; ++nf) {
        int colg = n0 + wn * 64 + nf * 16 + fr;
        float bv = bias[colg];
#pragma unroll
        for (int mf = 0; mf < 4; ++mf) {
            int rowbase = m0 + wm * 64 + mf * 16 + fg * 4;
#pragma unroll
            for (int j = 0; j < 4; ++j) {
                int rowg = rowbase + j;
                if (rowg < M) {
                    float v = fmaxf(acc[mf][nf][j] + bv, 0.f);
                    short hb, lb;
                    f2bf_split(v, hb, lb);
                    size_t idx = (size_t)rowg * H_F + colg;
                    Ch[idx] = hb;
                    Cl[idx] = lb;
                }
            }
        }
    }
}

// ---------------- relation GEMM: gload_lds DMA staging, dbuf, 1 barrier/K-step ----
// 1D grid, bijective XCD chunk swizzle; wgid -> (m, q) with q = (rel, nhalf) FASTEST,
// so the 10 blocks sharing one A m-panel run back-to-back on the SAME XCD (L2 reuse).
// LDS tiles [128][32] shorts, swizzled: 16B unit u of row r holds global unit
// (u - (r>>1)) & 3; read back at u = (fg + (r>>1)) & 3 -> 2-way banks.

__global__ __launch_bounds__(256, 2) void gemm_rel(
    const short* __restrict__ h1h, const short* __restrict__ h1l, long hopStride,
    const short* __restrict__ wch, const short* __restrict__ wcl,
    float* __restrict__ outB, const float* __restrict__ bcB, int M, int nwg)
{
    __shared__ short lds[2][4][128 * 32];

    // bijective XCD swizzle (m204): round-robin bid -> per-XCD contiguous wgid chunk
    const int bid = blockIdx.x;
    const int q8 = nwg >> 3, r8 = nwg & 7;
    const int xcd = bid & 7, idx = bid >> 3;
    const int wgid = (xcd < r8) ? (xcd * (q8 + 1) + idx)
                                : (r8 * (q8 + 1) + (xcd - r8) * q8 + idx);
    const int q = wgid % 10;
    const int mblk = wgid / 10;
    const int n0 = (q & 1) * 128;
    const int rrel = q >> 1;
    const int m0 = mblk * 128;

    const int tid = threadIdx.x;
    const int lane = tid & 63, wave = tid >> 6;
    const int wm = wave & 1, wn = wave >> 1;
    const int fr = lane & 15, fg = lane >> 4;

    const short* Agh = h1h + (size_t)rrel * hopStride;
    const short* Agl = h1l + (size_t)rrel * hopStride;
    const short* BTh = wch + (size_t)rrel * 256 * 768;
    const short* BTl = wcl + (size_t)rrel * 256 * 768;
    float* C = outB + (size_t)rrel * H_F;
    const float* bias = bcB + (size_t)rrel * H_F;

    // staging offsets (2 DMA calls per buffer per wave; call c covers rows c*16..c*16+15)
    int aoff[2], boff[2], loff[2];
#pragma unroll
    for (int p = 0; p < 2; ++p) {
        int c = wave * 2 + p;
        int r = c * 16 + (lane >> 2);
        int u = lane & 3;
        int g = (u - (r >> 1)) & 3;
        int ar = m0 + r; if (ar >= M) ar = M - 1;
        aoff[p] = ar * H_F + g * 8;        // A row stride 256 shorts
        boff[p] = (n0 + r) * 768 + g * 8;  // B row stride 768 shorts
        loff[p] = c * 512;                 // 1KB per call
    }

#define STAGE_REL(buf, kg) do {                                                  \
        int hop_ = (kg) >> 8, kin_ = (kg) & 255;                                 \
        const short* ah_ = Agh + (size_t)hop_ * hopStride + kin_;                \
        const short* al_ = Agl + (size_t)hop_ * hopStride + kin_;                \
        const short* bh_ = BTh + (kg);                                           \
        const short* bl_ = BTl + (kg);                                           \
        GLOAD16(ah_ + aoff[0], &lds[buf][0][loff[0]]);                           \
        GLOAD16(ah_ + aoff[1], &lds[buf][0][loff[1]]);                           \
        GLOAD16(al_ + aoff[0], &lds[buf][1][loff[0]]);                           \
        GLOAD16(al_ + aoff[1], &lds[buf][1][loff[1]]);                           \
        GLOAD16(bh_ + boff[0], &lds[buf][2][loff[0]]);                           \
        GLOAD16(bh_ + boff[1], &lds[buf][2][loff[1]]);                           \
        GLOAD16(bl_ + boff[0], &lds[buf][3][loff[0]]);                           \
        GLOAD16(bl_ + boff[1], &lds[buf][3][loff[1]]);                           \
    } while (0)

    f32x4 acc[4][4];
#pragma unroll
    for (int i = 0; i < 4; ++i)
#pragma unroll
        for (int j = 0; j < 4; ++j) acc[i][j] = (f32x4)0.f;

    STAGE_REL(0, 0);
    __syncthreads();  // drains vmcnt before first reads

    int cur = 0;
    const int nk = 768 / 32;  // 24
    for (int kt = 0; kt < nk; ++kt) {
        if (kt + 1 < nk) STAGE_REL(cur ^ 1, (kt + 1) * 32);

        const short* Ahc = &lds[cur][0][0];
        const short* Alc = &lds[cur][1][0];
        const short* Bhc = &lds[cur][2][0];
        const short* Blc = &lds[cur][3][0];

        short8 bfh[4], bfl[4];
#pragma unroll
        for (int nf = 0; nf < 4; ++nf) {
            int rb = wn * 64 + nf * 16 + fr;
            int ub = (fg + (rb >> 1)) & 3;
            bfh[nf] = *(const short8*)(Bhc + rb * 32 + ub * 8);
            bfl[nf] = *(const short8*)(Blc + rb * 32 + ub * 8);
        }
#pragma unroll
        for (int mf = 0; mf < 4; ++mf) {
            int ra = wm * 64 + mf * 16 + fr;
            int ua = (fg + (ra >> 1)) & 3;
            short8 ah = *(const short8*)(Ahc + ra * 32 + ua * 8);
            short8 al = *(const short8*)(Alc + ra * 32 + ua * 8);
#pragma unroll
            for (int nf = 0; nf < 4; ++nf) {
                acc[mf][nf] = __builtin_amdgcn_mfma_f32_16x16x32_bf16(
                    ah, bfh[nf], acc[mf][nf], 0, 0, 0);
                acc[mf][nf] = __builtin_amdgcn_mfma_f32_16x16x32_bf16(
                    ah, bfl[nf], acc[mf][nf], 0, 0, 0);
                acc[mf][nf] = __builtin_amdgcn_mfma_f32_16x16x32_bf16(
                    al, bfh[nf], acc[mf][nf], 0, 0, 0);
            }
        }
        __syncthreads();  // implicit vmcnt(0)+lgkmcnt(0) drain
        cur ^= 1;
    }

#pragma unroll
    for (int nf = 0; nf < 4; ++nf) {
        int colg = n0 + wn * 64 + nf * 16 + fr;
        float bv = bias[colg];
#pragma unroll
        for (int mf = 0; mf < 4; ++mf) {
            int rowbase = m0 + wm * 64 + mf * 16 + fg * 4;
#pragma unroll
            for (int j = 0; j < 4; ++j) {
                int rowg = rowbase + j;
                if (rowg < M)
                    C[(size_t)rowg * OUT_W + colg] = fmaxf(acc[mf][nf][j] + bv, 0.f);
            }
        }
    }
#undef STAGE_REL
}

// ---------------- fallback relation GEMM (pre-split A, reg-staged) ----------------
// MODE: 0 = bias, 2 = accum, 3 = accum+relu   (non-windowed path only)

template <int MODE>
__global__ __launch_bounds__(256, 2) void gemm_presplit(
    const short* __restrict__ Agh, const short* __restrict__ Agl, int lda,
    const short* __restrict__ BTh, const short* __restrict__ BTl, int ldb, int Kd,
    float* __restrict__ C, int ldc, const float* __restrict__ bias, int M)
{
    __shared__ short lds_buf[4 * 128 * LROW];
    short* Ah = lds_buf;
    short* Al = lds_buf + 128 * LROW;
    short* Bh = lds_buf + 2 * 128 * LROW;
    short* Bl = lds_buf + 3 * 128 * LROW;

    const int tid = threadIdx.x;
    const int lane = tid & 63, wave = tid >> 6;
    const int wm = wave & 1, wn = wave >> 1;
    const int fr = lane & 15, fg = lane >> 4;
    const int m0 = blockIdx.y * 128;
    const int n0 = blockIdx.x * 128;

    const int sr = tid >> 1;
    const int sc = (tid & 1) * 16;
    const bool avalid = (m0 + sr) < M;
    const int arow = avalid ? (m0 + sr) : (M - 1);

    short8 gah[2], gal[2], gbh[2], gbl[2];
    {
        const short* aph = Agh + (size_t)arow * lda + sc;
        const short* apl = Agl + (size_t)arow * lda + sc;
        const short* bph = BTh + (size_t)(n0 + sr) * ldb + sc;
        const short* bpl = BTl + (size_t)(n0 + sr) * ldb + sc;
        gah[0] = *(const short8*)aph;  gah[1] = *(const short8*)(aph + 8);
        gal[0] = *(const short8*)apl;  gal[1] = *(const short8*)(apl + 8);
        gbh[0] = *(const short8*)bph;  gbh[1] = *(const short8*)(bph + 8);
        gbl[0] = *(const short8*)bpl;  gbl[1] = *(const short8*)(bpl + 8);
    }

    f32x4 acc[4][4];
#pragma unroll
    for (int i = 0; i < 4; ++i)
#pragma unroll
        for (int j = 0; j < 4; ++j) acc[i][j] = (f32x4)0.f;

    const int nk = Kd / 32;
    for (int kk = 0; kk < nk; ++kk) {
        __syncthreads();
        *(short8*)(Ah + sr * LROW + sc)     = gah[0];
        *(short8*)(Ah + sr * LROW + sc + 8) = gah[1];
        *(short8*)(Al + sr * LROW + sc)     = gal[0];
        *(short8*)(Al + sr * LROW + sc + 8) = gal[1];
        *(short8*)(Bh + sr * LROW + sc)     = gbh[0];
        *(short8*)(Bh + sr * LROW + sc + 8) = gbh[1];
        *(short8*)(Bl + sr * LROW + sc)     = gbl[0];
        *(short8*)(Bl + sr * LROW + sc + 8) = gbl[1];
        __syncthreads();

        if (kk + 1 < nk) {
            int k0 = (kk + 1) * 32;
            const short* aph = Agh + (size_t)arow * lda + k0 + sc;
            const short* apl = Agl + (size_t)arow * lda + k0 + sc;
            const short* bph = BTh + (size_t)(n0 + sr) * ldb + k0 + sc;
            const short* bpl = BTl + (size_t)(n0 + sr) * ldb + k0 + sc;
            gah[0] = *(const short8*)aph;  gah[1] = *(const short8*)(aph + 8);
            gal[0] = *(const short8*)apl;  gal[1] = *(const short8*)(apl + 8);
            gbh[0] = *(const short8*)bph;  gbh[1] = *(const short8*)(bph + 8);
            gbl[0] = *(const short8*)bpl;  gbl[1] = *(const short8*)(bpl + 8);
        }

        short8 afh[4], afl[4], bfh[4], bfl[4];
#pragma unroll
        for (int mf = 0; mf < 4; ++mf) {
            int r = wm * 64 + mf * 16 + fr;
            afh[mf] = *(const short8*)(Ah + r * LROW + fg * 8);
            afl[mf] = *(const short8*)(Al + r * LROW + fg * 8);
        }
#pragma unroll
        for (int nf = 0; nf < 4; ++nf) {
            int r = wn * 64 + nf * 16 + fr;
            bfh[nf] = *(const short8*)(Bh + r * LROW + fg * 8);
            bfl[nf] = *(const short8*)(Bl + r * LROW + fg * 8);
        }
#pragma unroll
        for (int mf = 0; mf < 4; ++mf)
#pragma unroll
            for (int nf = 0; nf < 4; ++nf) {
                acc[mf][nf] = __builtin_amdgcn_mfma_f32_16x16x32_bf16(
                    afh[mf], bfh[nf], acc[mf][nf], 0, 0, 0);
                acc[mf][nf] = __builtin_amdgcn_mfma_f32_16x16x32_bf16(
                    afh[mf], bfl[nf], acc[mf][nf], 0, 0, 0);
                acc[mf][nf] = __builtin_amdgcn_mfma_f32_16x16x32_bf16(
                    afl[mf], bfh[nf], acc[mf][nf], 0, 0, 0);
            }
    }

#pragma unroll
    for (int nf = 0; nf < 4; ++nf) {
        int colg = n0 + wn * 64 + nf * 16 + fr;
        float bv = (MODE == 0) ? bias[colg] : 0.f;
#pragma unroll
        for (int mf = 0; mf < 4; ++mf) {
            int rowbase = m0 + wm * 64 + mf * 16 + fg * 4;
#pragma unroll
            for (int j = 0; j < 4; ++j) {
                int rowg = rowbase + j;
                if (rowg < M) {
                    size_t idx = (size_t)rowg * ldc + colg;
                    float v = acc[mf][nf][j] + bv;
                    if (MODE >= 2) v += C[idx];
                    if (MODE & 1) v = fmaxf(v, 0.f);
                    C[idx] = v;
                }
            }
        }
    }
}

// ---------------- driver ----------------

extern "C" void kernel_launch(void* const* d_in, const int* in_sizes, int n_in,
                              void* d_out, int out_size, void* d_ws, size_t ws_size,
                              hipStream_t stream) {
    const float* features = (const float*)d_in[0];
    const float* W1 = (const float*)d_in[1];
    const float* b1 = (const float*)d_in[2];
    const float* W2 = (const float*)d_in[3];
    const float* b2 = (const float*)d_in[4];
    const float* Wr = (const float*)d_in[5];
    const float* br = (const float*)d_in[6];
    const int* row = (const int*)d_in[7];
    const int* col = (const int*)d_in[8];
    float* out = (float*)d_out;

    // workspace layout (byte offsets; ws_size ~1953 MiB)
    char* ws = (char*)d_ws;
    int* deg = (int*)ws;                                 // 400KB (also cursor)
    int* rowptr = (int*)(ws + (1ull << 20));
    float* dinv = (float*)(ws + (2ull << 20));
    int* bsum = (int*)(ws + (3ull << 20));               // SCAN_B+1 ints
    int* cols2 = (int*)(ws + (4ull << 20));              // 6.4MB
    float* ew = (float*)(ws + (11ull << 20));            // 6.4MB
    short* w1h = (short*)(ws + (18ull << 20));           // 459KB
    short* w1l = (short*)(ws + (19ull << 20));
    float* wc32 = (float*)(ws + (20ull << 20));          // 3.93MB
    short* wch = (short*)(ws + (24ull << 20));           // 1.97MB
    short* wcl = (short*)(ws + (26ull << 20));
    float* bc = (float*)(ws + (28ull << 20));            // 5KB
    float* xa = (float*)(ws + (32ull << 20));            // 51.2MB
    float* xb = (float*)(ws + (96ull << 20));            // 51.2MB
    short* h1h = (short*)(ws + (160ull << 20));          // 341.8MiB (windowed)
    short* h1l = (short*)(ws + (576ull << 20));          // 341.8MiB

    const bool windowed = ws_size >= (1000ull << 20);

    // ---- adjacency normalization + CSR build ----
    zero_int<<<(N_NODES + 255) / 256, 256, 0, stream>>>(deg, N_NODES);
    deg_count<<<(E_EDGES + 255) / 256, 256, 0, stream>>>(row, deg);
    dinv_compute<<<(N_NODES + 255) / 256, 256, 0, stream>>>(deg, dinv);
    scan1<<<SCAN_B, 1024, 0, stream>>>(deg, rowptr, bsum);
    scan2<<<1, 64, 0, stream>>>(bsum);
    scan3<<<SCAN_B, 1024, 0, stream>>>(rowptr, bsum);
    zero_int<<<(N_NODES + 255) / 256, 256, 0, stream>>>(deg, N_NODES);
    csr_scatter<<<(E_EDGES + 255) / 256, 256, 0, stream>>>(row, col, dinv, rowptr,
                                                           deg, cols2, ew);

    // ---- weight fusion: Wc = W2 @ WrS, bc = br + b2 @ WrS ----
    wc_compute<<<dim3(15, H_F), 256, 0, stream>>>(W2, Wr, wc32);
    bc_compute<<<R_REL, 256, 0, stream>>>(b2, Wr, br, bc);

    // ---- weight transpose + bf16 split ----
    dim3 tb(32, 8);
    transpose_convert<<<dim3(IN_F / 32, 8, K_HOPS), tb, 0, stream>>>(W1, w1h, w1l, IN_F, 1);
    transpose_convert<<<dim3(H_F / 32, 8, 15), tb, 0, stream>>>(wc32, wch, wcl, H_F, 3);

    // ---- hop loop: MLP1 (fp32 A in, split bf16 out); then propagate ----
    const float* xcur = features;
    float* bufs[2] = {xa, xb};
    for (int k = 0; k < K_HOPS; ++k) {
        short* h1hd = windowed ? (h1h + (size_t)k * N_NODES * H_F) : h1h;
        short* h1ld = windowed ? (h1l + (size_t)k * N_NODES * H_F) : h1l;
        dim3 grid(2, (N_NODES + 127) / 128);
        gemm_mlp<<<grid, 256, 0, stream>>>(xcur, w1h + (size_t)k * 256 * IN_F,
                                           w1l + (size_t)k * 256 * IN_F,
                                           h1hd, h1ld, b1 + (size_t)k * H_F, N_NODES);

        if (!windowed) {
            int rlo = (k - 2 < 0) ? 0 : (k - 2);
            int rhi = (k < R_REL - 1) ? k : (R_REL - 1);
            for (int r = rlo; r <= rhi; ++r) {
                int d = k - r;
                const short* Bh = wch + (size_t)r * 256 * 768 + (size_t)d * H_F;
                const short* Bl = wcl + (size_t)r * 256 * 768 + (size_t)d * H_F;
                float* Cp = out + (size_t)r * H_F;
                if (k == r)
                    gemm_presplit<0><<<grid, 256, 0, stream>>>(
                        h1h, h1l, H_F, Bh, Bl, 768, H_F, Cp, OUT_W,
                        bc + (size_t)r * H_F, N_NODES);
                else if (k == r + 2)
                    gemm_presplit<3><<<grid, 256, 0, stream>>>(
                        h1h, h1l, H_F, Bh, Bl, 768, H_F, Cp, OUT_W, nullptr, N_NODES);
                else
                    gemm_presplit<2><<<grid, 256, 0, stream>>>(
                        h1h, h1l, H_F, Bh, Bl, 768, H_F, Cp, OUT_W, nullptr, N_NODES);
            }
        }

        if (k < K_HOPS - 1) {
            float* xn = bufs[k & 1];
            spmm_csr<<<(N_NODES + 3) / 4, 256, 0, stream>>>(
                (const float2*)xcur, rowptr, cols2, ew, dinv, (float2*)xn);
            xcur = xn;
        }
    }

    if (windowed) {
        // all 5 relation GEMMs in one 1D launch; XCD-chunked, q-fast for L2 reuse
        int mblocks = (N_NODES + 127) / 128;
        int nwg = mblocks * 2 * R_REL;
        gemm_rel<<<nwg, 256, 0, stream>>>(h1h, h1l, (long)N_NODES * H_F,
                                          wch, wcl, out, bc, N_NODES, nwg);
    }
}

// Round 8
// 2315.171 us; speedup vs baseline: 1.1865x; 1.0069x over previous
//
#include <hip/hip_runtime.h>

#define N_NODES 100000
#define E_EDGES 1600000
#define IN_F 128
#define H_F 256
#define K_HOPS 7
#define R_REL 5
#define OUT_W (R_REL * H_F)  // 1280
#define SCAN_B ((N_NODES + 1023) / 1024)  // 98

typedef __attribute__((ext_vector_type(8))) short short8;
typedef __attribute__((ext_vector_type(4))) float f32x4;

// async global->LDS, 16B per lane; lds dest = base + lane*16
#define GLOAD16(g, l) __builtin_amdgcn_global_load_lds( \
    (const __attribute__((address_space(1))) void*)(g), \
    (__attribute__((address_space(3))) void*)(l), 16, 0, 0)

// ---------------- small utility kernels ----------------

__global__ void zero_int(int* __restrict__ p, int n) {
    int t = blockIdx.x * blockDim.x + threadIdx.x;
    if (t < n) p[t] = 0;
}

__global__ void deg_count(const int* __restrict__ row, int* __restrict__ deg) {
    int e = blockIdx.x * blockDim.x + threadIdx.x;
    if (e < E_EDGES) atomicAdd(&deg[row[e]], 1);
}

__global__ void dinv_compute(const int* __restrict__ deg, float* __restrict__ dinv) {
    int i = blockIdx.x * blockDim.x + threadIdx.x;
    if (i < N_NODES) dinv[i] = rsqrtf((float)(deg[i] + 1));
}

// ---- 3-pass exclusive scan of deg -> rowptr ----
__global__ __launch_bounds__(1024) void scan1(const int* __restrict__ deg,
                                              int* __restrict__ rp, int* __restrict__ bsum) {
    __shared__ int ws[16];
    const int t = threadIdx.x, lane = t & 63, wv = t >> 6;
    int i = blockIdx.x * 1024 + t;
    int v = (i < N_NODES) ? deg[i] : 0;
    int x = v;
#pragma unroll
    for (int off = 1; off < 64; off <<= 1) {
        int n = __shfl_up(x, off, 64);
        if (lane >= off) x += n;
    }
    if (lane == 63) ws[wv] = x;
    __syncthreads();
    if (wv == 0 && lane < 16) {
        int s = ws[lane];
#pragma unroll
        for (int off = 1; off < 16; off <<= 1) {
            int n = __shfl_up(s, off, 64);
            if (lane >= off) s += n;
        }
        ws[lane] = s;
    }
    __syncthreads();
    int wbase = (wv == 0) ? 0 : ws[wv - 1];
    if (i < N_NODES) rp[i] = wbase + x - v;
    if (t == 1023) bsum[blockIdx.x] = ws[15];
}

// parallel scan of the 98 block sums (one block, 128 threads = 2 waves)
__global__ __launch_bounds__(128) void scan2(int* __restrict__ bsum) {
    __shared__ int wtot[2];
    const int t = threadIdx.x, lane = t & 63, wv = t >> 6;
    int v = (t < SCAN_B) ? bsum[t] : 0;
    int x = v;
#pragma unroll
    for (int off = 1; off < 64; off <<= 1) {
        int n = __shfl_up(x, off, 64);
        if (lane >= off) x += n;
    }
    if (lane == 63) wtot[wv] = x;
    __syncthreads();
    int base = (wv == 1) ? wtot[0] : 0;
    if (t < SCAN_B) bsum[t] = base + x - v;
    if (t == 127) bsum[SCAN_B] = wtot[0] + wtot[1];
}

__global__ __launch_bounds__(1024) void scan3(int* __restrict__ rp,
                                              const int* __restrict__ bsum) {
    int i = blockIdx.x * 1024 + threadIdx.x;
    if (i < N_NODES) rp[i] += bsum[blockIdx.x];
    if (i == 0) rp[N_NODES] = bsum[SCAN_B];
}

__global__ void csr_scatter(const int* __restrict__ row, const int* __restrict__ col,
                            const float* __restrict__ dinv, const int* __restrict__ rowptr,
                            int* __restrict__ cursor, int* __restrict__ cols2,
                            float* __restrict__ ew) {
    int e = blockIdx.x * blockDim.x + threadIdx.x;
    if (e >= E_EDGES) return;
    int r = row[e], c = col[e];
    int pos = rowptr[r] + atomicAdd(&cursor[r], 1);
    cols2[pos] = c;
    ew[pos] = dinv[r] * dinv[c];
}

// y[i] = dinv[i]^2 * x[i] + sum_j w[j] * x[cols[j]]   (one wave per row, float2/lane)
__global__ __launch_bounds__(256) void spmm_csr(
    const float2* __restrict__ x, const int* __restrict__ rowptr,
    const int* __restrict__ cols, const float* __restrict__ w,
    const float* __restrict__ dinv, float2* __restrict__ y) {
    const int wave = threadIdx.x >> 6, lane = threadIdx.x & 63;
    const int i = blockIdx.x * 4 + wave;
    if (i >= N_NODES) return;
    const float d = dinv[i];
    float2 xv = x[(size_t)i * 64 + lane];
    float2 acc;
    acc.x = d * d * xv.x;
    acc.y = d * d * xv.y;
    int j = rowptr[i];
    const int e = rowptr[i + 1];
    for (; j + 3 < e; j += 4) {
        int c0 = cols[j], c1 = cols[j + 1], c2 = cols[j + 2], c3 = cols[j + 3];
        float w0 = w[j], w1 = w[j + 1], w2 = w[j + 2], w3 = w[j + 3];
        float2 v0 = x[(size_t)c0 * 64 + lane];
        float2 v1 = x[(size_t)c1 * 64 + lane];
        float2 v2 = x[(size_t)c2 * 64 + lane];
        float2 v3 = x[(size_t)c3 * 64 + lane];
        acc.x += w0 * v0.x + w1 * v1.x + w2 * v2.x + w3 * v3.x;
        acc.y += w0 * v0.y + w1 * v1.y + w2 * v2.y + w3 * v3.y;
    }
    for (; j < e; ++j) {
        int c0 = cols[j];
        float w0 = w[j];
        float2 v0 = x[(size_t)c0 * 64 + lane];
        acc.x += w0 * v0.x;
        acc.y += w0 * v0.y;
    }
    y[(size_t)i * 64 + lane] = acc;
}

// ---------------- bf16 split helpers ----------------

__device__ __forceinline__ void f2bf_split(float v, short& h, short& l) {
    unsigned u = __float_as_uint(v);
    unsigned hb = (u + 0x7FFFu + ((u >> 16) & 1u)) >> 16;  // RN-to-even bf16
    float fh = __uint_as_float(hb << 16);
    float r = v - fh;
    unsigned u2 = __float_as_uint(r);
    unsigned lb = (u2 + 0x7FFFu + ((u2 >> 16) & 1u)) >> 16;
    h = (short)(unsigned short)hb;
    l = (short)(unsigned short)lb;
}

// ---------------- weight-fusion precompute ----------------
// Wc[z=r*3+d] = W2[r+d] @ WrS[r,d]
__global__ __launch_bounds__(256) void wc_compute(const float* __restrict__ W2,
                                                  const float* __restrict__ Wr,
                                                  float* __restrict__ Wc) {
    const int z = blockIdx.x, j = blockIdx.y, g = threadIdx.x;
    const int r = z / 3, d = z % 3, hop = r + d;
    const float* a = W2 + (size_t)hop * H_F * H_F + (size_t)j * H_F;
    const float* b = Wr + ((size_t)r * 768 + (size_t)d * H_F) * H_F + g;
    float acc = 0.f;
#pragma unroll 4
    for (int h = 0; h < H_F; ++h) acc += a[h] * b[(size_t)h * H_F];
    Wc[(size_t)z * H_F * H_F + (size_t)j * H_F + g] = acc;
}

// bc[r] = br[r] + sum_{d,h} b2[r+d][h] * WrS[r,d][h][:]
__global__ __launch_bounds__(256) void bc_compute(const float* __restrict__ b2,
                                                  const float* __restrict__ Wr,
                                                  const float* __restrict__ br,
                                                  float* __restrict__ bc) {
    const int r = blockIdx.x, g = threadIdx.x;
    float acc = br[(size_t)r * H_F + g];
    for (int t = 0; t < 3 * H_F; ++t) {
        float bv = b2[(size_t)(r + t / H_F) * H_F + (t % H_F)];
        acc += bv * Wr[((size_t)r * 768 + t) * H_F + g];
    }
    bc[(size_t)r * H_F + g] = acc;
}

// weight transpose+split: in [z][Kd][256] fp32 -> out group (z/grp) is [256][grp*Kd]
__global__ void transpose_convert(const float* __restrict__ in, short* __restrict__ oh,
                                  short* __restrict__ ol, int Kd, int grp) {
    __shared__ float t[32][33];
    const int i0 = blockIdx.x * 32, n0 = blockIdx.y * 32, z = blockIdx.z;
    const int tx = threadIdx.x, ty = threadIdx.y;
    const int outLd = grp * Kd;
    const float* ip = in + (size_t)z * Kd * 256;
#pragma unroll
    for (int j = 0; j < 4; ++j)
        t[ty + 8 * j][tx] = ip[(size_t)(i0 + ty + 8 * j) * 256 + n0 + tx];
    __syncthreads();
    size_t base = (size_t)(z / grp) * 256 * outLd + (size_t)(z % grp) * Kd;
#pragma unroll
    for (int j = 0; j < 4; ++j) {
        float v = t[tx][ty + 8 * j];
        short hb, lb;
        f2bf_split(v, hb, lb);
        size_t o = base + (size_t)(n0 + ty + 8 * j) * outLd + i0 + tx;
        oh[o] = hb;
        ol[o] = lb;
    }
}

// ---------------- MLP1 GEMM: fp32 A, in-kernel split, split-bf16 output ----------------
// Ch/Cl[M,256] = relu(A[M,128] @ B[128,256] + bias), reg-staged, LROW=40 pad

#define LROW 40

__global__ __launch_bounds__(256, 2) void gemm_mlp(
    const float* __restrict__ A,
    const short* __restrict__ BTh, const short* __restrict__ BTl,
    short* __restrict__ Ch, short* __restrict__ Cl,
    const float* __restrict__ bias, int M)
{
    __shared__ short lds_buf[4 * 128 * LROW];
    short* Ah = lds_buf;
    short* Al = lds_buf + 128 * LROW;
    short* Bh = lds_buf + 2 * 128 * LROW;
    short* Bl = lds_buf + 3 * 128 * LROW;

    const int tid = threadIdx.x;
    const int lane = tid & 63, wave = tid >> 6;
    const int wm = wave & 1, wn = wave >> 1;
    const int fr = lane & 15, fg = lane >> 4;
    const int m0 = blockIdx.y * 128;
    const int n0 = blockIdx.x * 128;

    const int sr = tid >> 1;
    const int sc = (tid & 1) * 16;
    const bool avalid = (m0 + sr) < M;
    const int arow = avalid ? (m0 + sr) : (M - 1);

    f32x4 ga[4];
    short8 gbh[2], gbl[2];
    {
        const float* ap = A + (size_t)arow * IN_F + sc;
        const short* bph = BTh + (size_t)(n0 + sr) * IN_F + sc;
        const short* bpl = BTl + (size_t)(n0 + sr) * IN_F + sc;
#pragma unroll
        for (int l = 0; l < 4; ++l) ga[l] = *(const f32x4*)(ap + 4 * l);
        gbh[0] = *(const short8*)bph;  gbh[1] = *(const short8*)(bph + 8);
        gbl[0] = *(const short8*)bpl;  gbl[1] = *(const short8*)(bpl + 8);
    }

    f32x4 acc[4][4];
#pragma unroll
    for (int i = 0; i < 4; ++i)
#pragma unroll
        for (int j = 0; j < 4; ++j) acc[i][j] = (f32x4)0.f;

    const int nk = IN_F / 32;  // 4
    for (int kk = 0; kk < nk; ++kk) {
        __syncthreads();
        {
            short8 vh[2], vl[2];
#pragma unroll
            for (int l = 0; l < 4; ++l) {
                f32x4 v = ga[l];
                if (!avalid) v = (f32x4)0.f;
#pragma unroll
                for (int e = 0; e < 4; ++e) {
                    short hb, lb;
                    f2bf_split(v[e], hb, lb);
                    vh[l >> 1][(l & 1) * 4 + e] = hb;
                    vl[l >> 1][(l & 1) * 4 + e] = lb;
                }
            }
            *(short8*)(Ah + sr * LROW + sc)     = vh[0];
            *(short8*)(Ah + sr * LROW + sc + 8) = vh[1];
            *(short8*)(Al + sr * LROW + sc)     = vl[0];
            *(short8*)(Al + sr * LROW + sc + 8) = vl[1];
            *(short8*)(Bh + sr * LROW + sc)     = gbh[0];
            *(short8*)(Bh + sr * LROW + sc + 8) = gbh[1];
            *(short8*)(Bl + sr * LROW + sc)     = gbl[0];
            *(short8*)(Bl + sr * LROW + sc + 8) = gbl[1];
        }
        __syncthreads();

        if (kk + 1 < nk) {
            int k0 = (kk + 1) * 32;
            const float* ap = A + (size_t)arow * IN_F + k0 + sc;
            const short* bph = BTh + (size_t)(n0 + sr) * IN_F + k0 + sc;
            const short* bpl = BTl + (size_t)(n0 + sr) * IN_F + k0 + sc;
#pragma unroll
            for (int l = 0; l < 4; ++l) ga[l] = *(const f32x4*)(ap + 4 * l);
            gbh[0] = *(const short8*)(bph);  gbh[1] = *(const short8*)(bph + 8);
            gbl[0] = *(const short8*)(bpl);  gbl[1] = *(const short8*)(bpl + 8);
        }

        short8 afh[4], afl[4], bfh[4], bfl[4];
#pragma unroll
        for (int mf = 0; mf < 4; ++mf) {
            int r = wm * 64 + mf * 16 + fr;
            afh[mf] = *(const short8*)(Ah + r * LROW + fg * 8);
            afl[mf] = *(const short8*)(Al + r * LROW + fg * 8);
        }
#pragma unroll
        for (int nf = 0; nf < 4; ++nf) {
            int r = wn * 64 + nf * 16 + fr;
            bfh[nf] = *(const short8*)(Bh + r * LROW + fg * 8);
            bfl[nf] = *(const short8*)(Bl + r * LROW + fg * 8);
        }
#pragma unroll
        for (int mf = 0; mf < 4; ++mf)
#pragma unroll
            for (int nf = 0; nf < 4; ++nf) {
                acc[mf][nf] = __builtin_amdgcn_mfma_f32_16x16x32_bf16(
                    afh[mf], bfh[nf], acc[mf][nf], 0, 0, 0);
                acc[mf][nf] = __builtin_amdgcn_mfma_f32_16x16x32_bf16(
                    afh[mf], bfl[nf], acc[mf][nf], 0, 0, 0);
                acc[mf][nf] = __builtin_amdgcn_mfma_f32_16x16x32_bf16(
                    afl[mf], bfh[nf], acc[mf][nf], 0, 0, 0);
            }
    }

#pragma unroll
    for (int nf = 0; nf < 4; ++nf) {
        int colg = n0 + wn * 64 + nf * 16 + fr;
        float bv = bias[colg];
#pragma unroll
        for (int mf = 0; mf < 4; ++mf) {
            int rowbase = m0 + wm * 64 + mf * 16 + fg * 4;
#pragma unroll
            for (int j = 0; j < 4; ++j) {
                int rowg = rowbase + j;
                if (rowg < M) {
                    float v = fmaxf(acc[mf][nf][j] + bv, 0.f);
                    short hb, lb;
                    f2bf_split(v, hb, lb);
                    size_t idx = (size_t)rowg * H_F + colg;
                    Ch[idx] = hb;
                    Cl[idx] = lb;
                }
            }
        }
    }
}

// ---------------- relation GEMM: gload_lds DMA staging, dbuf, 1 barrier/K-step ----
// 1D grid, bijective XCD chunk swizzle, q=(rel,nhalf) fastest (same-m blocks on 1 XCD).
// HOP-PHASE ROTATION: relation r starts its K-walk at k-step ROT(r) so at any instant
// the 5 relations read only ~2 distinct hop panels -> A panel L2-resident, fetched once.
// LDS tiles [128][32] shorts, swizzled: 16B unit u of row r holds global unit
// (u - (r>>1)) & 3; read back at u = (fg + (r>>1)) & 3 -> 2-way banks.

__global__ __launch_bounds__(256, 2) void gemm_rel(
    const short* __restrict__ h1h, const short* __restrict__ h1l, long hopStride,
    const short* __restrict__ wch, const short* __restrict__ wcl,
    float* __restrict__ outB, const float* __restrict__ bcB, int M, int nwg)
{
    __shared__ short lds[2][4][128 * 32];

    // bijective XCD swizzle (m204): round-robin bid -> per-XCD contiguous wgid chunk
    const int bid = blockIdx.x;
    const int q8 = nwg >> 3, r8 = nwg & 7;
    const int xcd = bid & 7, idx = bid >> 3;
    const int wgid = (xcd < r8) ? (xcd * (q8 + 1) + idx)
                                : (r8 * (q8 + 1) + (xcd - r8) * q8 + idx);
    const int q = wgid % 10;
    const int mblk = wgid / 10;
    const int n0 = (q & 1) * 128;
    const int rrel = q >> 1;
    const int m0 = mblk * 128;

    const int tid = threadIdx.x;
    const int lane = tid & 63, wave = tid >> 6;
    const int wm = wave & 1, wn = wave >> 1;
    const int fr = lane & 15, fg = lane >> 4;

    const short* Agh = h1h + (size_t)rrel * hopStride;
    const short* Agl = h1l + (size_t)rrel * hopStride;
    const short* BTh = wch + (size_t)rrel * 256 * 768;
    const short* BTl = wcl + (size_t)rrel * 256 * 768;
    float* C = outB + (size_t)rrel * H_F;
    const float* bias = bcB + (size_t)rrel * H_F;

    // hop-phase rotation start (in k-steps of 32): r=0..4 -> 0,16,8,0,16
    const int kstart = ((3 - (rrel % 3)) % 3) * 8;

    // staging offsets (2 DMA calls per buffer per wave; call c covers rows c*16..c*16+15)
    int aoff[2], boff[2], loff[2];
#pragma unroll
    for (int p = 0; p < 2; ++p) {
        int c = wave * 2 + p;
        int r = c * 16 + (lane >> 2);
        int u = lane & 3;
        int g = (u - (r >> 1)) & 3;
        int ar = m0 + r; if (ar >= M) ar = M - 1;
        aoff[p] = ar * H_F + g * 8;        // A row stride 256 shorts
        boff[p] = (n0 + r) * 768 + g * 8;  // B row stride 768 shorts
        loff[p] = c * 512;                 // 1KB per call
    }

#define STAGE_REL(buf, kg) do {                                                  \
        int hop_ = (kg) >> 8, kin_ = (kg) & 255;                                 \
        const short* ah_ = Agh + (size_t)hop_ * hopStride + kin_;                \
        const short* al_ = Agl + (size_t)hop_ * hopStride + kin_;                \
        const short* bh_ = BTh + (kg);                                           \
        const short* bl_ = BTl + (kg);                                           \
        GLOAD16(ah_ + aoff[0], &lds[buf][0][loff[0]]);                           \
        GLOAD16(ah_ + aoff[1], &lds[buf][0][loff[1]]);                           \
        GLOAD16(al_ + aoff[0], &lds[buf][1][loff[0]]);                           \
        GLOAD16(al_ + aoff[1], &lds[buf][1][loff[1]]);                           \
        GLOAD16(bh_ + boff[0], &lds[buf][2][loff[0]]);                           \
        GLOAD16(bh_ + boff[1], &lds[buf][2][loff[1]]);                           \
        GLOAD16(bl_ + boff[0], &lds[buf][3][loff[0]]);                           \
        GLOAD16(bl_ + boff[1], &lds[buf][3][loff[1]]);                           \
    } while (0)

    f32x4 acc[4][4];
#pragma unroll
    for (int i = 0; i < 4; ++i)
#pragma unroll
        for (int j = 0; j < 4; ++j) acc[i][j] = (f32x4)0.f;

    STAGE_REL(0, kstart * 32);
    __syncthreads();  // drains vmcnt before first reads

    int cur = 0;
    const int nk = 768 / 32;  // 24
    for (int kt = 0; kt < nk; ++kt) {
        if (kt + 1 < nk) {
            int kgn = ((kt + 1 + kstart) % nk) * 32;
            STAGE_REL(cur ^ 1, kgn);
        }

        const short* Ahc = &lds[cur][0][0];
        const short* Alc = &lds[cur][1][0];
        const short* Bhc = &lds[cur][2][0];
        const short* Blc = &lds[cur][3][0];

        short8 bfh[4], bfl[4];
#pragma unroll
        for (int nf = 0; nf < 4; ++nf) {
            int rb = wn * 64 + nf * 16 + fr;
            int ub = (fg + (rb >> 1)) & 3;
            bfh[nf] = *(const short8*)(Bhc + rb * 32 + ub * 8);
            bfl[nf] = *(const short8*)(Blc + rb * 32 + ub * 8);
        }
#pragma unroll
        for (int mf = 0; mf < 4; ++mf) {
            int ra = wm * 64 + mf * 16 + fr;
            int ua = (fg + (ra >> 1)) & 3;
            short8 ah = *(const short8*)(Ahc + ra * 32 + ua * 8);
            short8 al = *(const short8*)(Alc + ra * 32 + ua * 8);
#pragma unroll
            for (int nf = 0; nf < 4; ++nf) {
                acc[mf][nf] = __builtin_amdgcn_mfma_f32_16x16x32_bf16(
                    ah, bfh[nf], acc[mf][nf], 0, 0, 0);
                acc[mf][nf] = __builtin_amdgcn_mfma_f32_16x16x32_bf16(
                    ah, bfl[nf], acc[mf][nf], 0, 0, 0);
                acc[mf][nf] = __builtin_amdgcn_mfma_f32_16x16x32_bf16(
                    al, bfh[nf], acc[mf][nf], 0, 0, 0);
            }
        }
        __syncthreads();  // implicit vmcnt(0)+lgkmcnt(0) drain
        cur ^= 1;
    }

#pragma unroll
    for (int nf = 0; nf < 4; ++nf) {
        int colg = n0 + wn * 64 + nf * 16 + fr;
        float bv = bias[colg];
#pragma unroll
        for (int mf = 0; mf < 4; ++mf) {
            int rowbase = m0 + wm * 64 + mf * 16 + fg * 4;
#pragma unroll
            for (int j = 0; j < 4; ++j) {
                int rowg = rowbase + j;
                if (rowg < M)
                    C[(size_t)rowg * OUT_W + colg] = fmaxf(acc[mf][nf][j] + bv, 0.f);
            }
        }
    }
#undef STAGE_REL
}

// ---------------- fallback relation GEMM (pre-split A, reg-staged) ----------------
// MODE: 0 = bias, 2 = accum, 3 = accum+relu   (non-windowed path only)

template <int MODE>
__global__ __launch_bounds__(256, 2) void gemm_presplit(
    const short* __restrict__ Agh, const short* __restrict__ Agl, int lda,
    const short* __restrict__ BTh, const short* __restrict__ BTl, int ldb, int Kd,
    float* __restrict__ C, int ldc, const float* __restrict__ bias, int M)
{
    __shared__ short lds_buf[4 * 128 * LROW];
    short* Ah = lds_buf;
    short* Al = lds_buf + 128 * LROW;
    short* Bh = lds_buf + 2 * 128 * LROW;
    short* Bl = lds_buf + 3 * 128 * LROW;

    const int tid = threadIdx.x;
    const int lane = tid & 63, wave = tid >> 6;
    const int wm = wave & 1, wn = wave >> 1;
    const int fr = lane & 15, fg = lane >> 4;
    const int m0 = blockIdx.y * 128;
    const int n0 = blockIdx.x * 128;

    const int sr = tid >> 1;
    const int sc = (tid & 1) * 16;
    const bool avalid = (m0 + sr) < M;
    const int arow = avalid ? (m0 + sr) : (M - 1);

    short8 gah[2], gal[2], gbh[2], gbl[2];
    {
        const short* aph = Agh + (size_t)arow * lda + sc;
        const short* apl = Agl + (size_t)arow * lda + sc;
        const short* bph = BTh + (size_t)(n0 + sr) * ldb + sc;
        const short* bpl = BTl + (size_t)(n0 + sr) * ldb + sc;
        gah[0] = *(const short8*)aph;  gah[1] = *(const short8*)(aph + 8);
        gal[0] = *(const short8*)apl;  gal[1] = *(const short8*)(apl + 8);
        gbh[0] = *(const short8*)bph;  gbh[1] = *(const short8*)(bph + 8);
        gbl[0] = *(const short8*)bpl;  gbl[1] = *(const short8*)(bpl + 8);
    }

    f32x4 acc[4][4];
#pragma unroll
    for (int i = 0; i < 4; ++i)
#pragma unroll
        for (int j = 0; j < 4; ++j) acc[i][j] = (f32x4)0.f;

    const int nk = Kd / 32;
    for (int kk = 0; kk < nk; ++kk) {
        __syncthreads();
        *(short8*)(Ah + sr * LROW + sc)     = gah[0];
        *(short8*)(Ah + sr * LROW + sc + 8) = gah[1];
        *(short8*)(Al + sr * LROW + sc)     = gal[0];
        *(short8*)(Al + sr * LROW + sc + 8) = gal[1];
        *(short8*)(Bh + sr * LROW + sc)     = gbh[0];
        *(short8*)(Bh + sr * LROW + sc + 8) = gbh[1];
        *(short8*)(Bl + sr * LROW + sc)     = gbl[0];
        *(short8*)(Bl + sr * LROW + sc + 8) = gbl[1];
        __syncthreads();

        if (kk + 1 < nk) {
            int k0 = (kk + 1) * 32;
            const short* aph = Agh + (size_t)arow * lda + k0 + sc;
            const short* apl = Agl + (size_t)arow * lda + k0 + sc;
            const short* bph = BTh + (size_t)(n0 + sr) * ldb + k0 + sc;
            const short* bpl = BTl + (size_t)(n0 + sr) * ldb + k0 + sc;
            gah[0] = *(const short8*)aph;  gah[1] = *(const short8*)(aph + 8);
            gal[0] = *(const short8*)apl;  gal[1] = *(const short8*)(apl + 8);
            gbh[0] = *(const short8*)bph;  gbh[1] = *(const short8*)(bph + 8);
            gbl[0] = *(const short8*)bpl;  gbl[1] = *(const short8*)(bpl + 8);
        }

        short8 afh[4], afl[4], bfh[4], bfl[4];
#pragma unroll
        for (int mf = 0; mf < 4; ++mf) {
            int r = wm * 64 + mf * 16 + fr;
            afh[mf] = *(const short8*)(Ah + r * LROW + fg * 8);
            afl[mf] = *(const short8*)(Al + r * LROW + fg * 8);
        }
#pragma unroll
        for (int nf = 0; nf < 4; ++nf) {
            int r = wn * 64 + nf * 16 + fr;
            bfh[nf] = *(const short8*)(Bh + r * LROW + fg * 8);
            bfl[nf] = *(const short8*)(Bl + r * LROW + fg * 8);
        }
#pragma unroll
        for (int mf = 0; mf < 4; ++mf)
#pragma unroll
            for (int nf = 0; nf < 4; ++nf) {
                acc[mf][nf] = __builtin_amdgcn_mfma_f32_16x16x32_bf16(
                    afh[mf], bfh[nf], acc[mf][nf], 0, 0, 0);
                acc[mf][nf] = __builtin_amdgcn_mfma_f32_16x16x32_bf16(
                    afh[mf], bfl[nf], acc[mf][nf], 0, 0, 0);
                acc[mf][nf] = __builtin_amdgcn_mfma_f32_16x16x32_bf16(
                    afl[mf], bfh[nf], acc[mf][nf], 0, 0, 0);
            }
    }

#pragma unroll
    for (int nf = 0; nf < 4; ++nf) {
        int colg = n0 + wn * 64 + nf * 16 + fr;
        float bv = (MODE == 0) ? bias[colg] : 0.f;
#pragma unroll
        for (int mf = 0; mf < 4; ++mf) {
            int rowbase = m0 + wm * 64 + mf * 16 + fg * 4;
#pragma unroll
            for (int j = 0; j < 4; ++j) {
                int rowg = rowbase + j;
                if (rowg < M) {
                    size_t idx = (size_t)rowg * ldc + colg;
                    float v = acc[mf][nf][j] + bv;
                    if (MODE >= 2) v += C[idx];
                    if (MODE & 1) v = fmaxf(v, 0.f);
                    C[idx] = v;
                }
            }
        }
    }
}

// ---------------- driver ----------------

extern "C" void kernel_launch(void* const* d_in, const int* in_sizes, int n_in,
                              void* d_out, int out_size, void* d_ws, size_t ws_size,
                              hipStream_t stream) {
    const float* features = (const float*)d_in[0];
    const float* W1 = (const float*)d_in[1];
    const float* b1 = (const float*)d_in[2];
    const float* W2 = (const float*)d_in[3];
    const float* b2 = (const float*)d_in[4];
    const float* Wr = (const float*)d_in[5];
    const float* br = (const float*)d_in[6];
    const int* row = (const int*)d_in[7];
    const int* col = (const int*)d_in[8];
    float* out = (float*)d_out;

    // workspace layout (byte offsets; ws_size ~1953 MiB)
    char* ws = (char*)d_ws;
    int* deg = (int*)ws;                                 // 400KB (also cursor)
    int* rowptr = (int*)(ws + (1ull << 20));
    float* dinv = (float*)(ws + (2ull << 20));
    int* bsum = (int*)(ws + (3ull << 20));               // SCAN_B+1 ints
    int* cols2 = (int*)(ws + (4ull << 20));              // 6.4MB
    float* ew = (float*)(ws + (11ull << 20));            // 6.4MB
    short* w1h = (short*)(ws + (18ull << 20));           // 459KB
    short* w1l = (short*)(ws + (19ull << 20));
    float* wc32 = (float*)(ws + (20ull << 20));          // 3.93MB
    short* wch = (short*)(ws + (24ull << 20));           // 1.97MB
    short* wcl = (short*)(ws + (26ull << 20));
    float* bc = (float*)(ws + (28ull << 20));            // 5KB
    float* xa = (float*)(ws + (32ull << 20));            // 51.2MB
    float* xb = (float*)(ws + (96ull << 20));            // 51.2MB
    short* h1h = (short*)(ws + (160ull << 20));          // 341.8MiB (windowed)
    short* h1l = (short*)(ws + (576ull << 20));          // 341.8MiB

    const bool windowed = ws_size >= (1000ull << 20);

    // ---- adjacency normalization + CSR build ----
    zero_int<<<(N_NODES + 255) / 256, 256, 0, stream>>>(deg, N_NODES);
    deg_count<<<(E_EDGES + 255) / 256, 256, 0, stream>>>(row, deg);
    dinv_compute<<<(N_NODES + 255) / 256, 256, 0, stream>>>(deg, dinv);
    scan1<<<SCAN_B, 1024, 0, stream>>>(deg, rowptr, bsum);
    scan2<<<1, 128, 0, stream>>>(bsum);
    scan3<<<SCAN_B, 1024, 0, stream>>>(rowptr, bsum);
    zero_int<<<(N_NODES + 255) / 256, 256, 0, stream>>>(deg, N_NODES);
    csr_scatter<<<(E_EDGES + 255) / 256, 256, 0, stream>>>(row, col, dinv, rowptr,
                                                           deg, cols2, ew);

    // ---- weight fusion: Wc = W2 @ WrS, bc = br + b2 @ WrS ----
    wc_compute<<<dim3(15, H_F), 256, 0, stream>>>(W2, Wr, wc32);
    bc_compute<<<R_REL, 256, 0, stream>>>(b2, Wr, br, bc);

    // ---- weight transpose + bf16 split ----
    dim3 tb(32, 8);
    transpose_convert<<<dim3(IN_F / 32, 8, K_HOPS), tb, 0, stream>>>(W1, w1h, w1l, IN_F, 1);
    transpose_convert<<<dim3(H_F / 32, 8, 15), tb, 0, stream>>>(wc32, wch, wcl, H_F, 3);

    // ---- hop loop: MLP1 (fp32 A in, split bf16 out); then propagate ----
    const float* xcur = features;
    float* bufs[2] = {xa, xb};
    for (int k = 0; k < K_HOPS; ++k) {
        short* h1hd = windowed ? (h1h + (size_t)k * N_NODES * H_F) : h1h;
        short* h1ld = windowed ? (h1l + (size_t)k * N_NODES * H_F) : h1l;
        dim3 grid(2, (N_NODES + 127) / 128);
        gemm_mlp<<<grid, 256, 0, stream>>>(xcur, w1h + (size_t)k * 256 * IN_F,
                                           w1l + (size_t)k * 256 * IN_F,
                                           h1hd, h1ld, b1 + (size_t)k * H_F, N_NODES);

        if (!windowed) {
            int rlo = (k - 2 < 0) ? 0 : (k - 2);
            int rhi = (k < R_REL - 1) ? k : (R_REL - 1);
            for (int r = rlo; r <= rhi; ++r) {
                int d = k - r;
                const short* Bh = wch + (size_t)r * 256 * 768 + (size_t)d * H_F;
                const short* Bl = wcl + (size_t)r * 256 * 768 + (size_t)d * H_F;
                float* Cp = out + (size_t)r * H_F;
                if (k == r)
                    gemm_presplit<0><<<grid, 256, 0, stream>>>(
                        h1h, h1l, H_F, Bh, Bl, 768, H_F, Cp, OUT_W,
                        bc + (size_t)r * H_F, N_NODES);
                else if (k == r + 2)
                    gemm_presplit<3><<<grid, 256, 0, stream>>>(
                        h1h, h1l, H_F, Bh, Bl, 768, H_F, Cp, OUT_W, nullptr, N_NODES);
                else
                    gemm_presplit<2><<<grid, 256, 0, stream>>>(
                        h1h, h1l, H_F, Bh, Bl, 768, H_F, Cp, OUT_W, nullptr, N_NODES);
            }
        }

        if (k < K_HOPS - 1) {
            float* xn = bufs[k & 1];
            spmm_csr<<<(N_NODES + 3) / 4, 256, 0, stream>>>(
                (const float2*)xcur, rowptr, cols2, ew, dinv, (float2*)xn);
            xcur = xn;
        }
    }

    if (windowed) {
        // all 5 relation GEMMs in one 1D launch; XCD-chunked, q-fast, hop-rotated
        int mblocks = (N_NODES + 127) / 128;
        int nwg = mblocks * 2 * R_REL;
        gemm_rel<<<nwg, 256, 0, stream>>>(h1h, h1l, (long)N_NODES * H_F,
                                          wch, wcl, out, bc, N_NODES, nwg);
    }
}

// Round 9
// 2301.890 us; speedup vs baseline: 1.1933x; 1.0058x over previous
//
#include <hip/hip_runtime.h>

#define N_NODES 100000
#define E_EDGES 1600000
#define IN_F 128
#define H_F 256
#define K_HOPS 7
#define R_REL 5
#define OUT_W (R_REL * H_F)  // 1280
#define SCAN_B ((N_NODES + 1023) / 1024)  // 98

typedef __attribute__((ext_vector_type(8))) short short8;
typedef __attribute__((ext_vector_type(4))) float f32x4;

// async global->LDS, 16B per lane; lds dest = base + lane*16
#define GLOAD16(g, l) __builtin_amdgcn_global_load_lds( \
    (const __attribute__((address_space(1))) void*)(g), \
    (__attribute__((address_space(3))) void*)(l), 16, 0, 0)

// ---------------- small utility kernels ----------------

__global__ void zero_int(int* __restrict__ p, int n) {
    int t = blockIdx.x * blockDim.x + threadIdx.x;
    if (t < n) p[t] = 0;
}

__global__ void deg_count(const int* __restrict__ row, int* __restrict__ deg) {
    int e = blockIdx.x * blockDim.x + threadIdx.x;
    if (e < E_EDGES) atomicAdd(&deg[row[e]], 1);
}

__global__ void dinv_compute(const int* __restrict__ deg, float* __restrict__ dinv) {
    int i = blockIdx.x * blockDim.x + threadIdx.x;
    if (i < N_NODES) dinv[i] = rsqrtf((float)(deg[i] + 1));
}

// ---- 3-pass exclusive scan of deg -> rowptr ----
__global__ __launch_bounds__(1024) void scan1(const int* __restrict__ deg,
                                              int* __restrict__ rp, int* __restrict__ bsum) {
    __shared__ int ws[16];
    const int t = threadIdx.x, lane = t & 63, wv = t >> 6;
    int i = blockIdx.x * 1024 + t;
    int v = (i < N_NODES) ? deg[i] : 0;
    int x = v;
#pragma unroll
    for (int off = 1; off < 64; off <<= 1) {
        int n = __shfl_up(x, off, 64);
        if (lane >= off) x += n;
    }
    if (lane == 63) ws[wv] = x;
    __syncthreads();
    if (wv == 0 && lane < 16) {
        int s = ws[lane];
#pragma unroll
        for (int off = 1; off < 16; off <<= 1) {
            int n = __shfl_up(s, off, 64);
            if (lane >= off) s += n;
        }
        ws[lane] = s;
    }
    __syncthreads();
    int wbase = (wv == 0) ? 0 : ws[wv - 1];
    if (i < N_NODES) rp[i] = wbase + x - v;
    if (t == 1023) bsum[blockIdx.x] = ws[15];
}

// parallel scan of the 98 block sums (one block, 128 threads = 2 waves)
__global__ __launch_bounds__(128) void scan2(int* __restrict__ bsum) {
    __shared__ int wtot[2];
    const int t = threadIdx.x, lane = t & 63, wv = t >> 6;
    int v = (t < SCAN_B) ? bsum[t] : 0;
    int x = v;
#pragma unroll
    for (int off = 1; off < 64; off <<= 1) {
        int n = __shfl_up(x, off, 64);
        if (lane >= off) x += n;
    }
    if (lane == 63) wtot[wv] = x;
    __syncthreads();
    int base = (wv == 1) ? wtot[0] : 0;
    if (t < SCAN_B) bsum[t] = base + x - v;
    if (t == 127) bsum[SCAN_B] = wtot[0] + wtot[1];
}

__global__ __launch_bounds__(1024) void scan3(int* __restrict__ rp,
                                              const int* __restrict__ bsum) {
    int i = blockIdx.x * 1024 + threadIdx.x;
    if (i < N_NODES) rp[i] += bsum[blockIdx.x];
    if (i == 0) rp[N_NODES] = bsum[SCAN_B];
}

__global__ void csr_scatter(const int* __restrict__ row, const int* __restrict__ col,
                            const float* __restrict__ dinv, const int* __restrict__ rowptr,
                            int* __restrict__ cursor, int* __restrict__ cols2,
                            float* __restrict__ ew) {
    int e = blockIdx.x * blockDim.x + threadIdx.x;
    if (e >= E_EDGES) return;
    int r = row[e], c = col[e];
    int pos = rowptr[r] + atomicAdd(&cursor[r], 1);
    cols2[pos] = c;
    ew[pos] = dinv[r] * dinv[c];
}

// y[i] = dinv[i]^2 * x[i] + sum_j w[j] * x[cols[j]]   (one wave per row, float2/lane)
__global__ __launch_bounds__(256) void spmm_csr(
    const float2* __restrict__ x, const int* __restrict__ rowptr,
    const int* __restrict__ cols, const float* __restrict__ w,
    const float* __restrict__ dinv, float2* __restrict__ y) {
    const int wave = threadIdx.x >> 6, lane = threadIdx.x & 63;
    const int i = blockIdx.x * 4 + wave;
    if (i >= N_NODES) return;
    const float d = dinv[i];
    float2 xv = x[(size_t)i * 64 + lane];
    float2 acc;
    acc.x = d * d * xv.x;
    acc.y = d * d * xv.y;
    int j = rowptr[i];
    const int e = rowptr[i + 1];
    for (; j + 3 < e; j += 4) {
        int c0 = cols[j], c1 = cols[j + 1], c2 = cols[j + 2], c3 = cols[j + 3];
        float w0 = w[j], w1 = w[j + 1], w2 = w[j + 2], w3 = w[j + 3];
        float2 v0 = x[(size_t)c0 * 64 + lane];
        float2 v1 = x[(size_t)c1 * 64 + lane];
        float2 v2 = x[(size_t)c2 * 64 + lane];
        float2 v3 = x[(size_t)c3 * 64 + lane];
        acc.x += w0 * v0.x + w1 * v1.x + w2 * v2.x + w3 * v3.x;
        acc.y += w0 * v0.y + w1 * v1.y + w2 * v2.y + w3 * v3.y;
    }
    for (; j < e; ++j) {
        int c0 = cols[j];
        float w0 = w[j];
        float2 v0 = x[(size_t)c0 * 64 + lane];
        acc.x += w0 * v0.x;
        acc.y += w0 * v0.y;
    }
    y[(size_t)i * 64 + lane] = acc;
}

// ---------------- bf16 split helpers ----------------

__device__ __forceinline__ void f2bf_split(float v, short& h, short& l) {
    unsigned u = __float_as_uint(v);
    unsigned hb = (u + 0x7FFFu + ((u >> 16) & 1u)) >> 16;  // RN-to-even bf16
    float fh = __uint_as_float(hb << 16);
    float r = v - fh;
    unsigned u2 = __float_as_uint(r);
    unsigned lb = (u2 + 0x7FFFu + ((u2 >> 16) & 1u)) >> 16;
    h = (short)(unsigned short)hb;
    l = (short)(unsigned short)lb;
}

// ---------------- weight-fusion precompute ----------------
// Wc[z=r*3+d] = W2[r+d] @ WrS[r,d]
__global__ __launch_bounds__(256) void wc_compute(const float* __restrict__ W2,
                                                  const float* __restrict__ Wr,
                                                  float* __restrict__ Wc) {
    const int z = blockIdx.x, j = blockIdx.y, g = threadIdx.x;
    const int r = z / 3, d = z % 3, hop = r + d;
    const float* a = W2 + (size_t)hop * H_F * H_F + (size_t)j * H_F;
    const float* b = Wr + ((size_t)r * 768 + (size_t)d * H_F) * H_F + g;
    float acc = 0.f;
#pragma unroll 4
    for (int h = 0; h < H_F; ++h) acc += a[h] * b[(size_t)h * H_F];
    Wc[(size_t)z * H_F * H_F + (size_t)j * H_F + g] = acc;
}

// bc[r] = br[r] + sum_{d,h} b2[r+d][h] * WrS[r,d][h][:]
__global__ __launch_bounds__(256) void bc_compute(const float* __restrict__ b2,
                                                  const float* __restrict__ Wr,
                                                  const float* __restrict__ br,
                                                  float* __restrict__ bc) {
    const int r = blockIdx.x, g = threadIdx.x;
    float acc = br[(size_t)r * H_F + g];
    for (int t = 0; t < 3 * H_F; ++t) {
        float bv = b2[(size_t)(r + t / H_F) * H_F + (t % H_F)];
        acc += bv * Wr[((size_t)r * 768 + t) * H_F + g];
    }
    bc[(size_t)r * H_F + g] = acc;
}

// weight transpose+split: in [z][Kd][256] fp32 -> out group (z/grp) is [256][grp*Kd]
__global__ void transpose_convert(const float* __restrict__ in, short* __restrict__ oh,
                                  short* __restrict__ ol, int Kd, int grp) {
    __shared__ float t[32][33];
    const int i0 = blockIdx.x * 32, n0 = blockIdx.y * 32, z = blockIdx.z;
    const int tx = threadIdx.x, ty = threadIdx.y;
    const int outLd = grp * Kd;
    const float* ip = in + (size_t)z * Kd * 256;
#pragma unroll
    for (int j = 0; j < 4; ++j)
        t[ty + 8 * j][tx] = ip[(size_t)(i0 + ty + 8 * j) * 256 + n0 + tx];
    __syncthreads();
    size_t base = (size_t)(z / grp) * 256 * outLd + (size_t)(z % grp) * Kd;
#pragma unroll
    for (int j = 0; j < 4; ++j) {
        float v = t[tx][ty + 8 * j];
        short hb, lb;
        f2bf_split(v, hb, lb);
        size_t o = base + (size_t)(n0 + ty + 8 * j) * outLd + i0 + tx;
        oh[o] = hb;
        ol[o] = lb;
    }
}

// ---------------- MLP1 GEMM: fp32 A, in-kernel split, split-bf16 output ----------------
// Ch/Cl[M,256] = relu(A[M,128] @ B[128,256] + bias), reg-staged, LROW=40 pad

#define LROW 40

__global__ __launch_bounds__(256, 2) void gemm_mlp(
    const float* __restrict__ A,
    const short* __restrict__ BTh, const short* __restrict__ BTl,
    short* __restrict__ Ch, short* __restrict__ Cl,
    const float* __restrict__ bias, int M)
{
    __shared__ short lds_buf[4 * 128 * LROW];
    short* Ah = lds_buf;
    short* Al = lds_buf + 128 * LROW;
    short* Bh = lds_buf + 2 * 128 * LROW;
    short* Bl = lds_buf + 3 * 128 * LROW;

    const int tid = threadIdx.x;
    const int lane = tid & 63, wave = tid >> 6;
    const int wm = wave & 1, wn = wave >> 1;
    const int fr = lane & 15, fg = lane >> 4;
    const int m0 = blockIdx.y * 128;
    const int n0 = blockIdx.x * 128;

    const int sr = tid >> 1;
    const int sc = (tid & 1) * 16;
    const bool avalid = (m0 + sr) < M;
    const int arow = avalid ? (m0 + sr) : (M - 1);

    f32x4 ga[4];
    short8 gbh[2], gbl[2];
    {
        const float* ap = A + (size_t)arow * IN_F + sc;
        const short* bph = BTh + (size_t)(n0 + sr) * IN_F + sc;
        const short* bpl = BTl + (size_t)(n0 + sr) * IN_F + sc;
#pragma unroll
        for (int l = 0; l < 4; ++l) ga[l] = *(const f32x4*)(ap + 4 * l);
        gbh[0] = *(const short8*)bph;  gbh[1] = *(const short8*)(bph + 8);
        gbl[0] = *(const short8*)bpl;  gbl[1] = *(const short8*)(bpl + 8);
    }

    f32x4 acc[4][4];
#pragma unroll
    for (int i = 0; i < 4; ++i)
#pragma unroll
        for (int j = 0; j < 4; ++j) acc[i][j] = (f32x4)0.f;

    const int nk = IN_F / 32;  // 4
    for (int kk = 0; kk < nk; ++kk) {
        __syncthreads();
        {
            short8 vh[2], vl[2];
#pragma unroll
            for (int l = 0; l < 4; ++l) {
                f32x4 v = ga[l];
                if (!avalid) v = (f32x4)0.f;
#pragma unroll
                for (int e = 0; e < 4; ++e) {
                    short hb, lb;
                    f2bf_split(v[e], hb, lb);
                    vh[l >> 1][(l & 1) * 4 + e] = hb;
                    vl[l >> 1][(l & 1) * 4 + e] = lb;
                }
            }
            *(short8*)(Ah + sr * LROW + sc)     = vh[0];
            *(short8*)(Ah + sr * LROW + sc + 8) = vh[1];
            *(short8*)(Al + sr * LROW + sc)     = vl[0];
            *(short8*)(Al + sr * LROW + sc + 8) = vl[1];
            *(short8*)(Bh + sr * LROW + sc)     = gbh[0];
            *(short8*)(Bh + sr * LROW + sc + 8) = gbh[1];
            *(short8*)(Bl + sr * LROW + sc)     = gbl[0];
            *(short8*)(Bl + sr * LROW + sc + 8) = gbl[1];
        }
        __syncthreads();

        if (kk + 1 < nk) {
            int k0 = (kk + 1) * 32;
            const float* ap = A + (size_t)arow * IN_F + k0 + sc;
            const short* bph = BTh + (size_t)(n0 + sr) * IN_F + k0 + sc;
            const short* bpl = BTl + (size_t)(n0 + sr) * IN_F + k0 + sc;
#pragma unroll
            for (int l = 0; l < 4; ++l) ga[l] = *(const f32x4*)(ap + 4 * l);
            gbh[0] = *(const short8*)(bph);  gbh[1] = *(const short8*)(bph + 8);
            gbl[0] = *(const short8*)(bpl);  gbl[1] = *(const short8*)(bpl + 8);
        }

        short8 afh[4], afl[4], bfh[4], bfl[4];
#pragma unroll
        for (int mf = 0; mf < 4; ++mf) {
            int r = wm * 64 + mf * 16 + fr;
            afh[mf] = *(const short8*)(Ah + r * LROW + fg * 8);
            afl[mf] = *(const short8*)(Al + r * LROW + fg * 8);
        }
#pragma unroll
        for (int nf = 0; nf < 4; ++nf) {
            int r = wn * 64 + nf * 16 + fr;
            bfh[nf] = *(const short8*)(Bh + r * LROW + fg * 8);
            bfl[nf] = *(const short8*)(Bl + r * LROW + fg * 8);
        }
#pragma unroll
        for (int mf = 0; mf < 4; ++mf)
#pragma unroll
            for (int nf = 0; nf < 4; ++nf) {
                acc[mf][nf] = __builtin_amdgcn_mfma_f32_16x16x32_bf16(
                    afh[mf], bfh[nf], acc[mf][nf], 0, 0, 0);
                acc[mf][nf] = __builtin_amdgcn_mfma_f32_16x16x32_bf16(
                    afh[mf], bfl[nf], acc[mf][nf], 0, 0, 0);
                acc[mf][nf] = __builtin_amdgcn_mfma_f32_16x16x32_bf16(
                    afl[mf], bfh[nf], acc[mf][nf], 0, 0, 0);
            }
    }

#pragma unroll
    for (int nf = 0; nf < 4; ++nf) {
        int colg = n0 + wn * 64 + nf * 16 + fr;
        float bv = bias[colg];
#pragma unroll
        for (int mf = 0; mf < 4; ++mf) {
            int rowbase = m0 + wm * 64 + mf * 16 + fg * 4;
#pragma unroll
            for (int j = 0; j < 4; ++j) {
                int rowg = rowbase + j;
                if (rowg < M) {
                    float v = fmaxf(acc[mf][nf][j] + bv, 0.f);
                    short hb, lb;
                    f2bf_split(v, hb, lb);
                    size_t idx = (size_t)rowg * H_F + colg;
                    Ch[idx] = hb;
                    Cl[idx] = lb;
                }
            }
        }
    }
}

// ---------------- relation GEMM: counted-vmcnt dbuf schedule (T3+T4+T5) ----------
// 1D grid, bijective XCD chunk swizzle, q=(rel,nhalf) fastest; hop-phase rotation.
// Per k-step: vmcnt(8) [next tile's 8 loads stay in flight] -> s_barrier ->
// ds_read + 48 MFMA (setprio 1) -> s_barrier -> STAGE(kt+2 into this buffer).
// LDS tiles [128][32] shorts, swizzled: 16B unit u of row r holds global unit
// (u - (r>>1)) & 3; read back at u = (fg + (r>>1)) & 3 -> 2-way banks.

__global__ __launch_bounds__(256, 2) void gemm_rel(
    const short* __restrict__ h1h, const short* __restrict__ h1l, long hopStride,
    const short* __restrict__ wch, const short* __restrict__ wcl,
    float* __restrict__ outB, const float* __restrict__ bcB, int M, int nwg)
{
    __shared__ short lds[2][4][128 * 32];

    // bijective XCD swizzle (m204): round-robin bid -> per-XCD contiguous wgid chunk
    const int bid = blockIdx.x;
    const int q8 = nwg >> 3, r8 = nwg & 7;
    const int xcd = bid & 7, idx = bid >> 3;
    const int wgid = (xcd < r8) ? (xcd * (q8 + 1) + idx)
                                : (r8 * (q8 + 1) + (xcd - r8) * q8 + idx);
    const int q = wgid % 10;
    const int mblk = wgid / 10;
    const int n0 = (q & 1) * 128;
    const int rrel = q >> 1;
    const int m0 = mblk * 128;

    const int tid = threadIdx.x;
    const int lane = tid & 63, wave = tid >> 6;
    const int wm = wave & 1, wn = wave >> 1;
    const int fr = lane & 15, fg = lane >> 4;

    const short* Agh = h1h + (size_t)rrel * hopStride;
    const short* Agl = h1l + (size_t)rrel * hopStride;
    const short* BTh = wch + (size_t)rrel * 256 * 768;
    const short* BTl = wcl + (size_t)rrel * 256 * 768;
    float* C = outB + (size_t)rrel * H_F;
    const float* bias = bcB + (size_t)rrel * H_F;

    // hop-phase rotation start (in k-steps of 32): r=0..4 -> 0,16,8,0,16
    const int kstart = ((3 - (rrel % 3)) % 3) * 8;

    // staging offsets (2 DMA calls per buffer per wave; call c covers rows c*16..c*16+15)
    int aoff[2], boff[2], loff[2];
#pragma unroll
    for (int p = 0; p < 2; ++p) {
        int c = wave * 2 + p;
        int r = c * 16 + (lane >> 2);
        int u = lane & 3;
        int g = (u - (r >> 1)) & 3;
        int ar = m0 + r; if (ar >= M) ar = M - 1;
        aoff[p] = ar * H_F + g * 8;        // A row stride 256 shorts
        boff[p] = (n0 + r) * 768 + g * 8;  // B row stride 768 shorts
        loff[p] = c * 512;                 // 1KB per call
    }

#define STAGE_REL(buf, kg) do {                                                  \
        int hop_ = (kg) >> 8, kin_ = (kg) & 255;                                 \
        const short* ah_ = Agh + (size_t)hop_ * hopStride + kin_;                \
        const short* al_ = Agl + (size_t)hop_ * hopStride + kin_;                \
        const short* bh_ = BTh + (kg);                                           \
        const short* bl_ = BTl + (kg);                                           \
        GLOAD16(ah_ + aoff[0], &lds[buf][0][loff[0]]);                           \
        GLOAD16(ah_ + aoff[1], &lds[buf][0][loff[1]]);                           \
        GLOAD16(al_ + aoff[0], &lds[buf][1][loff[0]]);                           \
        GLOAD16(al_ + aoff[1], &lds[buf][1][loff[1]]);                           \
        GLOAD16(bh_ + boff[0], &lds[buf][2][loff[0]]);                           \
        GLOAD16(bh_ + boff[1], &lds[buf][2][loff[1]]);                           \
        GLOAD16(bl_ + boff[0], &lds[buf][3][loff[0]]);                           \
        GLOAD16(bl_ + boff[1], &lds[buf][3][loff[1]]);                           \
    } while (0)

#define KIDX(t) ((((t) + kstart) % nk) * 32)

    f32x4 acc[4][4];
#pragma unroll
    for (int i = 0; i < 4; ++i)
#pragma unroll
        for (int j = 0; j < 4; ++j) acc[i][j] = (f32x4)0.f;

    const int nk = 768 / 32;  // 24

    // prologue: fill both buffers; 16 loads in flight
    STAGE_REL(0, KIDX(0));
    STAGE_REL(1, KIDX(1));

    int cur = 0;
    for (int kt = 0; kt < nk; ++kt) {
        // wait for buf[cur]'s 8 loads; leave the next tile's 8 in flight (T4)
        if (kt + 1 < nk) {
            asm volatile("s_waitcnt vmcnt(8)" ::: "memory");
        } else {
            asm volatile("s_waitcnt vmcnt(0)" ::: "memory");
        }
        __builtin_amdgcn_sched_barrier(0);
        __builtin_amdgcn_s_barrier();          // all waves' buf[cur] data published
        __builtin_amdgcn_sched_barrier(0);

        const short* Ahc = &lds[cur][0][0];
        const short* Alc = &lds[cur][1][0];
        const short* Bhc = &lds[cur][2][0];
        const short* Blc = &lds[cur][3][0];

        short8 bfh[4], bfl[4];
#pragma unroll
        for (int nf = 0; nf < 4; ++nf) {
            int rb = wn * 64 + nf * 16 + fr;
            int ub = (fg + (rb >> 1)) & 3;
            bfh[nf] = *(const short8*)(Bhc + rb * 32 + ub * 8);
            bfl[nf] = *(const short8*)(Blc + rb * 32 + ub * 8);
        }
        __builtin_amdgcn_s_setprio(1);
#pragma unroll
        for (int mf = 0; mf < 4; ++mf) {
            int ra = wm * 64 + mf * 16 + fr;
            int ua = (fg + (ra >> 1)) & 3;
            short8 ah = *(const short8*)(Ahc + ra * 32 + ua * 8);
            short8 al = *(const short8*)(Alc + ra * 32 + ua * 8);
#pragma unroll
            for (int nf = 0; nf < 4; ++nf) {
                acc[mf][nf] = __builtin_amdgcn_mfma_f32_16x16x32_bf16(
                    ah, bfh[nf], acc[mf][nf], 0, 0, 0);
                acc[mf][nf] = __builtin_amdgcn_mfma_f32_16x16x32_bf16(
                    ah, bfl[nf], acc[mf][nf], 0, 0, 0);
                acc[mf][nf] = __builtin_amdgcn_mfma_f32_16x16x32_bf16(
                    al, bfh[nf], acc[mf][nf], 0, 0, 0);
            }
        }
        __builtin_amdgcn_s_setprio(0);

        __builtin_amdgcn_sched_barrier(0);
        __builtin_amdgcn_s_barrier();          // all waves' reads of buf[cur] done
        __builtin_amdgcn_sched_barrier(0);

        if (kt + 2 < nk) STAGE_REL(cur, KIDX(kt + 2));  // overwrite now safe
        cur ^= 1;
    }

#pragma unroll
    for (int nf = 0; nf < 4; ++nf) {
        int colg = n0 + wn * 64 + nf * 16 + fr;
        float bv = bias[colg];
#pragma unroll
        for (int mf = 0; mf < 4; ++mf) {
            int rowbase = m0 + wm * 64 + mf * 16 + fg * 4;
#pragma unroll
            for (int j = 0; j < 4; ++j) {
                int rowg = rowbase + j;
                if (rowg < M)
                    C[(size_t)rowg * OUT_W + colg] = fmaxf(acc[mf][nf][j] + bv, 0.f);
            }
        }
    }
#undef STAGE_REL
#undef KIDX
}

// ---------------- fallback relation GEMM (pre-split A, reg-staged) ----------------
// MODE: 0 = bias, 2 = accum, 3 = accum+relu   (non-windowed path only)

template <int MODE>
__global__ __launch_bounds__(256, 2) void gemm_presplit(
    const short* __restrict__ Agh, const short* __restrict__ Agl, int lda,
    const short* __restrict__ BTh, const short* __restrict__ BTl, int ldb, int Kd,
    float* __restrict__ C, int ldc, const float* __restrict__ bias, int M)
{
    __shared__ short lds_buf[4 * 128 * LROW];
    short* Ah = lds_buf;
    short* Al = lds_buf + 128 * LROW;
    short* Bh = lds_buf + 2 * 128 * LROW;
    short* Bl = lds_buf + 3 * 128 * LROW;

    const int tid = threadIdx.x;
    const int lane = tid & 63, wave = tid >> 6;
    const int wm = wave & 1, wn = wave >> 1;
    const int fr = lane & 15, fg = lane >> 4;
    const int m0 = blockIdx.y * 128;
    const int n0 = blockIdx.x * 128;

    const int sr = tid >> 1;
    const int sc = (tid & 1) * 16;
    const bool avalid = (m0 + sr) < M;
    const int arow = avalid ? (m0 + sr) : (M - 1);

    short8 gah[2], gal[2], gbh[2], gbl[2];
    {
        const short* aph = Agh + (size_t)arow * lda + sc;
        const short* apl = Agl + (size_t)arow * lda + sc;
        const short* bph = BTh + (size_t)(n0 + sr) * ldb + sc;
        const short* bpl = BTl + (size_t)(n0 + sr) * ldb + sc;
        gah[0] = *(const short8*)aph;  gah[1] = *(const short8*)(aph + 8);
        gal[0] = *(const short8*)apl;  gal[1] = *(const short8*)(apl + 8);
        gbh[0] = *(const short8*)bph;  gbh[1] = *(const short8*)(bph + 8);
        gbl[0] = *(const short8*)bpl;  gbl[1] = *(const short8*)(bpl + 8);
    }

    f32x4 acc[4][4];
#pragma unroll
    for (int i = 0; i < 4; ++i)
#pragma unroll
        for (int j = 0; j < 4; ++j) acc[i][j] = (f32x4)0.f;

    const int nk = Kd / 32;
    for (int kk = 0; kk < nk; ++kk) {
        __syncthreads();
        *(short8*)(Ah + sr * LROW + sc)     = gah[0];
        *(short8*)(Ah + sr * LROW + sc + 8) = gah[1];
        *(short8*)(Al + sr * LROW + sc)     = gal[0];
        *(short8*)(Al + sr * LROW + sc + 8) = gal[1];
        *(short8*)(Bh + sr * LROW + sc)     = gbh[0];
        *(short8*)(Bh + sr * LROW + sc + 8) = gbh[1];
        *(short8*)(Bl + sr * LROW + sc)     = gbl[0];
        *(short8*)(Bl + sr * LROW + sc + 8) = gbl[1];
        __syncthreads();

        if (kk + 1 < nk) {
            int k0 = (kk + 1) * 32;
            const short* aph = Agh + (size_t)arow * lda + k0 + sc;
            const short* apl = Agl + (size_t)arow * lda + k0 + sc;
            const short* bph = BTh + (size_t)(n0 + sr) * ldb + k0 + sc;
            const short* bpl = BTl + (size_t)(n0 + sr) * ldb + k0 + sc;
            gah[0] = *(const short8*)aph;  gah[1] = *(const short8*)(aph + 8);
            gal[0] = *(const short8*)apl;  gal[1] = *(const short8*)(apl + 8);
            gbh[0] = *(const short8*)bph;  gbh[1] = *(const short8*)(bph + 8);
            gbl[0] = *(const short8*)bpl;  gbl[1] = *(const short8*)(bpl + 8);
        }

        short8 afh[4], afl[4], bfh[4], bfl[4];
#pragma unroll
        for (int mf = 0; mf < 4; ++mf) {
            int r = wm * 64 + mf * 16 + fr;
            afh[mf] = *(const short8*)(Ah + r * LROW + fg * 8);
            afl[mf] = *(const short8*)(Al + r * LROW + fg * 8);
        }
#pragma unroll
        for (int nf = 0; nf < 4; ++nf) {
            int r = wn * 64 + nf * 16 + fr;
            bfh[nf] = *(const short8*)(Bh + r * LROW + fg * 8);
            bfl[nf] = *(const short8*)(Bl + r * LROW + fg * 8);
        }
#pragma unroll
        for (int mf = 0; mf < 4; ++mf)
#pragma unroll
            for (int nf = 0; nf < 4; ++nf) {
                acc[mf][nf] = __builtin_amdgcn_mfma_f32_16x16x32_bf16(
                    afh[mf], bfh[nf], acc[mf][nf], 0, 0, 0);
                acc[mf][nf] = __builtin_amdgcn_mfma_f32_16x16x32_bf16(
                    afh[mf], bfl[nf], acc[mf][nf], 0, 0, 0);
                acc[mf][nf] = __builtin_amdgcn_mfma_f32_16x16x32_bf16(
                    afl[mf], bfh[nf], acc[mf][nf], 0, 0, 0);
            }
    }

#pragma unroll
    for (int nf = 0; nf < 4; ++nf) {
        int colg = n0 + wn * 64 + nf * 16 + fr;
        float bv = (MODE == 0) ? bias[colg] : 0.f;
#pragma unroll
        for (int mf = 0; mf < 4; ++mf) {
            int rowbase = m0 + wm * 64 + mf * 16 + fg * 4;
#pragma unroll
            for (int j = 0; j < 4; ++j) {
                int rowg = rowbase + j;
                if (rowg < M) {
                    size_t idx = (size_t)rowg * ldc + colg;
                    float v = acc[mf][nf][j] + bv;
                    if (MODE >= 2) v += C[idx];
                    if (MODE & 1) v = fmaxf(v, 0.f);
                    C[idx] = v;
                }
            }
        }
    }
}

// ---------------- driver ----------------

extern "C" void kernel_launch(void* const* d_in, const int* in_sizes, int n_in,
                              void* d_out, int out_size, void* d_ws, size_t ws_size,
                              hipStream_t stream) {
    const float* features = (const float*)d_in[0];
    const float* W1 = (const float*)d_in[1];
    const float* b1 = (const float*)d_in[2];
    const float* W2 = (const float*)d_in[3];
    const float* b2 = (const float*)d_in[4];
    const float* Wr = (const float*)d_in[5];
    const float* br = (const float*)d_in[6];
    const int* row = (const int*)d_in[7];
    const int* col = (const int*)d_in[8];
    float* out = (float*)d_out;

    // workspace layout (byte offsets; ws_size ~1953 MiB)
    char* ws = (char*)d_ws;
    int* deg = (int*)ws;                                 // 400KB (also cursor)
    int* rowptr = (int*)(ws + (1ull << 20));
    float* dinv = (float*)(ws + (2ull << 20));
    int* bsum = (int*)(ws + (3ull << 20));               // SCAN_B+1 ints
    int* cols2 = (int*)(ws + (4ull << 20));              // 6.4MB
    float* ew = (float*)(ws + (11ull << 20));            // 6.4MB
    short* w1h = (short*)(ws + (18ull << 20));           // 459KB
    short* w1l = (short*)(ws + (19ull << 20));
    float* wc32 = (float*)(ws + (20ull << 20));          // 3.93MB
    short* wch = (short*)(ws + (24ull << 20));           // 1.97MB
    short* wcl = (short*)(ws + (26ull << 20));
    float* bc = (float*)(ws + (28ull << 20));            // 5KB
    float* xa = (float*)(ws + (32ull << 20));            // 51.2MB
    float* xb = (float*)(ws + (96ull << 20));            // 51.2MB
    short* h1h = (short*)(ws + (160ull << 20));          // 341.8MiB (windowed)
    short* h1l = (short*)(ws + (576ull << 20));          // 341.8MiB

    const bool windowed = ws_size >= (1000ull << 20);

    // ---- adjacency normalization + CSR build ----
    zero_int<<<(N_NODES + 255) / 256, 256, 0, stream>>>(deg, N_NODES);
    deg_count<<<(E_EDGES + 255) / 256, 256, 0, stream>>>(row, deg);
    dinv_compute<<<(N_NODES + 255) / 256, 256, 0, stream>>>(deg, dinv);
    scan1<<<SCAN_B, 1024, 0, stream>>>(deg, rowptr, bsum);
    scan2<<<1, 128, 0, stream>>>(bsum);
    scan3<<<SCAN_B, 1024, 0, stream>>>(rowptr, bsum);
    zero_int<<<(N_NODES + 255) / 256, 256, 0, stream>>>(deg, N_NODES);
    csr_scatter<<<(E_EDGES + 255) / 256, 256, 0, stream>>>(row, col, dinv, rowptr,
                                                           deg, cols2, ew);

    // ---- weight fusion: Wc = W2 @ WrS, bc = br + b2 @ WrS ----
    wc_compute<<<dim3(15, H_F), 256, 0, stream>>>(W2, Wr, wc32);
    bc_compute<<<R_REL, 256, 0, stream>>>(b2, Wr, br, bc);

    // ---- weight transpose + bf16 split ----
    dim3 tb(32, 8);
    transpose_convert<<<dim3(IN_F / 32, 8, K_HOPS), tb, 0, stream>>>(W1, w1h, w1l, IN_F, 1);
    transpose_convert<<<dim3(H_F / 32, 8, 15), tb, 0, stream>>>(wc32, wch, wcl, H_F, 3);

    // ---- hop loop: MLP1 (fp32 A in, split bf16 out); then propagate ----
    const float* xcur = features;
    float* bufs[2] = {xa, xb};
    for (int k = 0; k < K_HOPS; ++k) {
        short* h1hd = windowed ? (h1h + (size_t)k * N_NODES * H_F) : h1h;
        short* h1ld = windowed ? (h1l + (size_t)k * N_NODES * H_F) : h1l;
        dim3 grid(2, (N_NODES + 127) / 128);
        gemm_mlp<<<grid, 256, 0, stream>>>(xcur, w1h + (size_t)k * 256 * IN_F,
                                           w1l + (size_t)k * 256 * IN_F,
                                           h1hd, h1ld, b1 + (size_t)k * H_F, N_NODES);

        if (!windowed) {
            int rlo = (k - 2 < 0) ? 0 : (k - 2);
            int rhi = (k < R_REL - 1) ? k : (R_REL - 1);
            for (int r = rlo; r <= rhi; ++r) {
                int d = k - r;
                const short* Bh = wch + (size_t)r * 256 * 768 + (size_t)d * H_F;
                const short* Bl = wcl + (size_t)r * 256 * 768 + (size_t)d * H_F;
                float* Cp = out + (size_t)r * H_F;
                if (k == r)
                    gemm_presplit<0><<<grid, 256, 0, stream>>>(
                        h1h, h1l, H_F, Bh, Bl, 768, H_F, Cp, OUT_W,
                        bc + (size_t)r * H_F, N_NODES);
                else if (k == r + 2)
                    gemm_presplit<3><<<grid, 256, 0, stream>>>(
                        h1h, h1l, H_F, Bh, Bl, 768, H_F, Cp, OUT_W, nullptr, N_NODES);
                else
                    gemm_presplit<2><<<grid, 256, 0, stream>>>(
                        h1h, h1l, H_F, Bh, Bl, 768, H_F, Cp, OUT_W, nullptr, N_NODES);
            }
        }

        if (k < K_HOPS - 1) {
            float* xn = bufs[k & 1];
            spmm_csr<<<(N_NODES + 3) / 4, 256, 0, stream>>>(
                (const float2*)xcur, rowptr, cols2, ew, dinv, (float2*)xn);
            xcur = xn;
        }
    }

    if (windowed) {
        // all 5 relation GEMMs in one 1D launch; XCD-chunked, q-fast, hop-rotated
        int mblocks = (N_NODES + 127) / 128;
        int nwg = mblocks * 2 * R_REL;
        gemm_rel<<<nwg, 256, 0, stream>>>(h1h, h1l, (long)N_NODES * H_F,
                                          wch, wcl, out, bc, N_NODES, nwg);
    }
}